// Round 11
// baseline (200.003 us; speedup 1.0000x reference)
//
#include <hip/hip_runtime.h>
#include <hip/hip_bf16.h>

#define RS 0.9999950000374998f  // 1/sqrt(1+1e-5)

__device__ __forceinline__ float eluf(float x) {
    return x > 0.0f ? x : __expf(x) - 1.0f;
}

typedef __attribute__((ext_vector_type(8))) __bf16 bf16x8;
typedef __attribute__((ext_vector_type(4))) float f32x4;
typedef __attribute__((ext_vector_type(4))) unsigned int u32x4;

// ---------------------------------------------------------------------------
// f32-input tiled GEMM (fts_l). OUTB=1 -> bf16 output.
// ---------------------------------------------------------------------------
template <int ACT, int BN, int OUTB>
__global__ __launch_bounds__(256) void gemm_bias_act(
    const float* __restrict__ A, const float* __restrict__ W,
    const float* __restrict__ bias, const float* __restrict__ gamma,
    const float* __restrict__ beta, void* __restrict__ outp,
    int Kdim, int Ncols) {
    __shared__ float As[16][64];
    __shared__ float Bs[16][64];
    const int tid = threadIdx.x;
    const int tx = tid & 15, ty = tid >> 4;
    const long row0 = (long)blockIdx.x * 64;
    const int col0 = blockIdx.y * 64;
    const int rA = tid >> 2, kqA = (tid & 3) << 2;
    const int kkB = tid >> 4, cqB = (tid & 15) << 2;
    float acc[4][4] = {};
    for (int k0 = 0; k0 < Kdim; k0 += 16) {
        const float4 av = *reinterpret_cast<const float4*>(
            A + (row0 + rA) * (long)Kdim + (k0 + kqA));
        const float4 bv = *reinterpret_cast<const float4*>(
            W + (long)(k0 + kkB) * Ncols + (col0 + cqB));
        As[kqA + 0][rA] = av.x;
        As[kqA + 1][rA] = av.y;
        As[kqA + 2][rA] = av.z;
        As[kqA + 3][rA] = av.w;
        *reinterpret_cast<float4*>(&Bs[kkB][cqB]) = bv;
        __syncthreads();
#pragma unroll
        for (int kk = 0; kk < 16; ++kk) {
            float a[4], b[4];
#pragma unroll
            for (int i = 0; i < 4; ++i) a[i] = As[kk][ty * 4 + i];
#pragma unroll
            for (int j = 0; j < 4; ++j) b[j] = Bs[kk][tx * 4 + j];
#pragma unroll
            for (int i = 0; i < 4; ++i)
#pragma unroll
                for (int j = 0; j < 4; ++j) acc[i][j] = fmaf(a[i], b[j], acc[i][j]);
        }
        __syncthreads();
    }
#pragma unroll
    for (int j = 0; j < 4; ++j) {
        const int col = col0 + tx * 4 + j;
        const float bb = bias[col];
        const float gs = BN ? gamma[col] * RS : 0.0f;
        const float bt = BN ? beta[col] : 0.0f;
#pragma unroll
        for (int i = 0; i < 4; ++i) {
            const long row = row0 + ty * 4 + i;
            float v = acc[i][j] + bb;
            if (ACT) v = eluf(v);
            if (BN) v = v * gs + bt;
            if (OUTB)
                reinterpret_cast<__hip_bfloat16*>(outp)[row * Ncols + col] =
                    __float2bfloat16(v);
            else
                reinterpret_cast<float*>(outp)[row * Ncols + col] = v;
        }
    }
}

// ---------------------------------------------------------------------------
// Weight conversion to bf16-transposed forms. One-shot, tiny.
// ---------------------------------------------------------------------------
__global__ __launch_bounds__(256) void convert_weights(
    const float* __restrict__ d1W, const float* __restrict__ d2W,
    const float* __restrict__ pwW, const float* __restrict__ d2Ws,
    __hip_bfloat16* __restrict__ d1Wt, __hip_bfloat16* __restrict__ d2Wt,
    __hip_bfloat16* __restrict__ pwWt, __hip_bfloat16* __restrict__ d2pWt) {
    const int t = blockIdx.x * 256 + threadIdx.x;
    if (t < 65536) {
        const int k = t >> 8, n = t & 255;
        d1Wt[n * 256 + k] = __float2bfloat16(d1W[t]);
        d2Wt[n * 256 + k] = __float2bfloat16(d2W[t]);
    }
    if (t < 24576) {
        const int k = t >> 7, n = t & 127;
        pwWt[n * 192 + k] = __float2bfloat16(pwW[t]);
    }
    if (t < 1024) {
        const int q = t >> 5, c = t & 31;
        d2pWt[c * 32 + q] = __float2bfloat16(d2Ws[t]);
    }
}

// ---------------------------------------------------------------------------
// bf16 MFMA GEMM (R7 winner): out = post(A @ Wt^T + bias), Wt pre-transposed.
// Tile 128x128, BK=32, 4 waves.
// ---------------------------------------------------------------------------
template <int ACT, int BN_, int OUTB>
__global__ __launch_bounds__(256) void mfma_gemm(
    const __hip_bfloat16* __restrict__ A, const __hip_bfloat16* __restrict__ Wt,
    const float* __restrict__ bias, const float* __restrict__ gamma,
    const float* __restrict__ beta, void* __restrict__ outp, int K, int Ncols) {
    __shared__ __bf16 As[128][40];
    __shared__ __bf16 Bs[128][40];
    const int tid = threadIdx.x;
    const int w = tid >> 6, l = tid & 63;
    const int wm = w >> 1, wn = w & 1;
    const long row0 = (long)blockIdx.x * 128;
    const int col0 = blockIdx.y * 128;
    const int sr = tid >> 1, sh = tid & 1;
    const int fr = l & 15, kg = (l >> 4) * 8;
    f32x4 acc[4][4] = {};
    const __hip_bfloat16* __restrict__ ap = A + (row0 + sr) * (long)K + sh * 16;
    const __hip_bfloat16* __restrict__ bp =
        Wt + (long)(col0 + sr) * K + sh * 16;
    for (int k0 = 0; k0 < K; k0 += 32) {
        const uint4 av0 = *reinterpret_cast<const uint4*>(ap + k0);
        const uint4 av1 = *reinterpret_cast<const uint4*>(ap + k0 + 8);
        const uint4 bv0 = *reinterpret_cast<const uint4*>(bp + k0);
        const uint4 bv1 = *reinterpret_cast<const uint4*>(bp + k0 + 8);
        *reinterpret_cast<uint4*>(&As[sr][sh * 16]) = av0;
        *reinterpret_cast<uint4*>(&As[sr][sh * 16 + 8]) = av1;
        *reinterpret_cast<uint4*>(&Bs[sr][sh * 16]) = bv0;
        *reinterpret_cast<uint4*>(&Bs[sr][sh * 16 + 8]) = bv1;
        __syncthreads();
        bf16x8 af[4], bfv[4];
#pragma unroll
        for (int mt = 0; mt < 4; ++mt)
            af[mt] =
                *reinterpret_cast<const bf16x8*>(&As[wm * 64 + mt * 16 + fr][kg]);
#pragma unroll
        for (int nt = 0; nt < 4; ++nt)
            bfv[nt] =
                *reinterpret_cast<const bf16x8*>(&Bs[wn * 64 + nt * 16 + fr][kg]);
#pragma unroll
        for (int mt = 0; mt < 4; ++mt)
#pragma unroll
            for (int nt = 0; nt < 4; ++nt)
                acc[mt][nt] = __builtin_amdgcn_mfma_f32_16x16x32_bf16(
                    af[mt], bfv[nt], acc[mt][nt], 0, 0, 0);
        __syncthreads();
    }
    const int rg = (l >> 4) * 4;
#pragma unroll
    for (int nt = 0; nt < 4; ++nt) {
        const int col = col0 + wn * 64 + nt * 16 + fr;
        const float bb = bias[col];
        const float gs = BN_ ? gamma[col] * RS : 0.0f;
        const float bt = BN_ ? beta[col] : 0.0f;
#pragma unroll
        for (int mt = 0; mt < 4; ++mt) {
#pragma unroll
            for (int r = 0; r < 4; ++r) {
                const long row = row0 + wm * 64 + mt * 16 + rg + r;
                float v = acc[mt][nt][r] + bb;
                if (ACT) v = eluf(v);
                if (BN_) v = v * gs + bt;
                if (OUTB)
                    reinterpret_cast<__hip_bfloat16*>(outp)[row * Ncols + col] =
                        __float2bfloat16(v);
                else
                    reinterpret_cast<float*>(outp)[row * Ncols + col] = v;
            }
        }
    }
}

// ---------------------------------------------------------------------------
// Setup: pts_local (f32 store) + Xc (bf16 store). 16 pts/block, grid 2048.
// ---------------------------------------------------------------------------
__global__ __launch_bounds__(256) void setup_kernel(
    const float* __restrict__ rep_pts, const float* __restrict__ pts,
    const int* __restrict__ pts_idx, const float* __restrict__ xt_cW,
    const float* __restrict__ xt_cb, float* __restrict__ pts_local,
    __hip_bfloat16* __restrict__ Xc) {
    __shared__ float cwT[48][256];
    __shared__ float pl2[16][48];
    __shared__ float cb_s[256];
    const int tid = threadIdx.x;
    const long gp0 = (long)blockIdx.x * 16;
#pragma unroll
    for (int i = 0; i < 48; ++i) {
        const int e = i * 256 + tid;
        const int o = e / 48, r = e - o * 48;
        cwT[r][o] = xt_cW[e];
    }
    cb_s[tid] = xt_cb[tid];
    {
        const int pt = tid >> 4, k = tid & 15;
        const long gp = gp0 + pt;
        const int n = (int)(gp >> 11);
        const int idx = pts_idx[gp * 32 + 2 * k];
        const float* ps = pts + ((long)n * 8192 + idx) * 3;
        const float* rs = rep_pts + gp * 3;
        float* plo = pts_local + gp * 48 + k * 3;
#pragma unroll
        for (int d = 0; d < 3; ++d) {
            const float v = ps[d] - rs[d];
            pl2[pt][d * 16 + k] = v;
            plo[d] = v;
        }
    }
    __syncthreads();
    const int o = tid;
    for (int pt = 0; pt < 16; ++pt) {
        float acc = cb_s[o];
#pragma unroll
        for (int i = 0; i < 48; ++i) acc = fmaf(pl2[pt][i], cwT[i][o], acc);
        Xc[(gp0 + pt) * 256 + o] = __float2bfloat16(eluf(acc));
    }
}

// ---------------------------------------------------------------------------
// Final per-point stage v9: 2 points per wave, SMEM-free body.
// Grid 4096 x 4 waves (R9 residency regime). idx rows loaded as per-lane
// VECTOR loads (vmcnt) and redistributed via v_readlane (VALU) so no scalar
// memory op is in flight while fcat DS ops execute (lgkmcnt isolation).
// Both points' idx/pl/X/gather loads issue before any compute; the two
// points then compute back-to-back reusing fcat (in-wave DS ordering, no
// barriers).
// NOTE: no 2nd __launch_bounds__ arg (R4: (256,4) clamp -> 64 VGPR spill).
// ---------------------------------------------------------------------------
__global__ __launch_bounds__(256) void final_stage_kernel(
    const __hip_bfloat16* __restrict__ X2B,  // [32768][256] bf16
    const float* __restrict__ pts_local,     // [32768][48] (k*3+d)
    const int* __restrict__ pts_idx,
    const __hip_bfloat16* __restrict__ fts_lB,  // [131072][64] bf16
    const float* __restrict__ d1_W, const float* __restrict__ d1_b,
    const float* __restrict__ d1_g, const float* __restrict__ d1_bt,
    const __hip_bfloat16* __restrict__ d2pWt,  // [32 c][32 q] bf16
    const float* __restrict__ d2_b, const float* __restrict__ d2_g,
    const float* __restrict__ d2_bt, const float* __restrict__ dw_W,
    const float* __restrict__ dw_b,
    __hip_bfloat16* __restrict__ dw_out)  // [32768][192] bf16
{
    __shared__ __bf16 fcat[4][96][24];  // wave-private

    const int tid = threadIdx.x;
    const int w = tid >> 6, l = tid & 63;
    const int obid = blockIdx.x;
    const int bid = (obid & 7) * 512 + (obid >> 3);  // bijective, 4096%8==0
    const int g0 = __builtin_amdgcn_readfirstlane((bid * 4 + w) * 2);
    const int g1 = g0 + 1;
    const int n = g0 >> 11;  // pair within one batch (g0 even)
    const int fr = l & 15;
    const int kg = (l >> 4) * 8;
    const int kk = kg & 15;
    const unsigned msk = (l < 32) ? 0xFFFFFFFFu : 0u;
    const int rg4 = (l >> 4) * 4;
    const int colg = (l < 32) ? (32 + l) : (l - 32);
    const __hip_bfloat16* __restrict__ fbase =
        fts_lB + (long)n * 8192 * 64 + colg;

    // ---- issue ALL long-latency loads up front (vector, vmcnt only) ----
    const int j16 = l & 15;
    const int iv0 = pts_idx[(long)g0 * 32 + 2 * j16];  // lane j16 holds idx[j16]
    const int iv1 = pts_idx[(long)g1 * 32 + 2 * j16];
    const float* __restrict__ pp0 = pts_local + (long)g0 * 48 + fr * 3;
    const float pl00 = pp0[0], pl01 = pp0[1], pl02 = pp0[2];
    const float* __restrict__ pp1 = pts_local + (long)g1 * 48 + fr * 3;
    const float pl10 = pp1[0], pl11 = pp1[1], pl12 = pp1[2];
    const u32x4 ax0 =
        *reinterpret_cast<const u32x4*>(X2B + (long)g0 * 256 + fr * 16 + kk);
    const u32x4 ax1 =
        *reinterpret_cast<const u32x4*>(X2B + (long)g1 * 256 + fr * 16 + kk);

    // gathers: idx redistributed via v_readlane (uniform -> SGPR base, no SMEM)
    unsigned fg0[16], fg1[16];
#pragma unroll
    for (int j = 0; j < 16; ++j) {
        const int s0 = __builtin_amdgcn_readlane(iv0, j);
        fg0[j] = *reinterpret_cast<const unsigned short*>(
            &fbase[(long)s0 * 64]);
    }
#pragma unroll
    for (int j = 0; j < 16; ++j) {
        const int s1 = __builtin_amdgcn_readlane(iv1, j);
        fg1[j] = *reinterpret_cast<const unsigned short*>(
            &fbase[(long)s1 * 64]);
    }

    // ---- process one point (all state in regs/fcat[w]) ----
    auto process = [&](int gp, float p0, float p1, float p2, u32x4 axv,
                       const unsigned* fg) {
        // l0 row-owner A-frag: lane = row fr, k-cols kg..kg+7
        bf16x8 a_l0;
#pragma unroll
        for (int jj = 0; jj < 8; ++jj) {
            const int q = kg + jj;
            float a = d1_b[q];
            a = fmaf(p0, d1_W[q], a);
            a = fmaf(p1, d1_W[32 + q], a);
            a = fmaf(p2, d1_W[64 + q], a);
            a = eluf(a);
            a = a * (d1_g[q] * RS) + d1_bt[q];
            a_l0[jj] = (__bf16)a;
        }

        // lifted = l0 @ d2_W via 2 MFMA (K=32 exact) -> fcat cols 0..31
        {
            const bf16x8 b0 =
                *reinterpret_cast<const bf16x8*>(d2pWt + (0 + fr) * 32 + kg);
            const bf16x8 b1 =
                *reinterpret_cast<const bf16x8*>(d2pWt + (16 + fr) * 32 + kg);
            f32x4 lif0 = {}, lif1 = {};
            lif0 =
                __builtin_amdgcn_mfma_f32_16x16x32_bf16(a_l0, b0, lif0, 0, 0, 0);
            lif1 =
                __builtin_amdgcn_mfma_f32_16x16x32_bf16(a_l0, b1, lif1, 0, 0, 0);
#pragma unroll
            for (int f = 0; f < 2; ++f) {
                const int c = f * 16 + fr;
                const float bb = d2_b[c], gs = d2_g[c] * RS, bt = d2_bt[c];
                const f32x4 dd = f ? lif1 : lif0;
                unsigned short pk[4];
#pragma unroll
                for (int r = 0; r < 4; ++r) {
                    float v = dd[r] + bb;
                    v = eluf(v) * gs + bt;
                    const __bf16 h = (__bf16)v;
                    pk[r] = *reinterpret_cast<const unsigned short*>(&h);
                }
                *reinterpret_cast<uint2*>(&fcat[w][c][rg4]) =
                    make_uint2((unsigned)pk[0] | ((unsigned)pk[1] << 16),
                               (unsigned)pk[2] | ((unsigned)pk[3] << 16));
            }
        }

        // fg (bf16 bits) -> fcat[32+colg][0..15] (2 x ds_write_b128)
        {
            const uint4 lo =
                make_uint4(fg[0] | (fg[1] << 16), fg[2] | (fg[3] << 16),
                           fg[4] | (fg[5] << 16), fg[6] | (fg[7] << 16));
            const uint4 hi =
                make_uint4(fg[8] | (fg[9] << 16), fg[10] | (fg[11] << 16),
                           fg[12] | (fg[13] << 16), fg[14] | (fg[15] << 16));
            *reinterpret_cast<uint4*>(&fcat[w][32 + colg][0]) = lo;
            *reinterpret_cast<uint4*>(&fcat[w][32 + colg][8]) = hi;
        }

        // A-frag: X row fr (zero k>=16 half via mask)
        u32x4 axu = axv & msk;
        const bf16x8 ax = *reinterpret_cast<const bf16x8*>(&axu);

        // fts_X: 6 B-frags from fcat + 6 MFMA
        f32x4 acc[6];
#pragma unroll
        for (int f = 0; f < 6; ++f) acc[f] = (f32x4){};
#pragma unroll
        for (int f = 0; f < 6; ++f) {
            u32x4 bu =
                *reinterpret_cast<const u32x4*>(&fcat[w][f * 16 + fr][kk]);
            bu &= msk;  // zero k>=16 (also kills uninit-LDS NaN)
            const bf16x8 bf = *reinterpret_cast<const bf16x8*>(&bu);
            acc[f] =
                __builtin_amdgcn_mfma_f32_16x16x32_bf16(ax, bf, acc[f], 0, 0, 0);
        }

        // dw: partials rows rg4..rg4+3, butterfly, store (lanes<16)
        float dwv[6][2];
#pragma unroll
        for (int f = 0; f < 6; ++f) {
            const int c = f * 16 + fr;
            const float4 w0 =
                *reinterpret_cast<const float4*>(dw_W + c * 32 + rg4);
            const float4 w1 =
                *reinterpret_cast<const float4*>(dw_W + c * 32 + 16 + rg4);
            float q0 = acc[f][0] * w0.x;
            q0 = fmaf(acc[f][1], w0.y, q0);
            q0 = fmaf(acc[f][2], w0.z, q0);
            q0 = fmaf(acc[f][3], w0.w, q0);
            float q1 = acc[f][0] * w1.x;
            q1 = fmaf(acc[f][1], w1.y, q1);
            q1 = fmaf(acc[f][2], w1.z, q1);
            q1 = fmaf(acc[f][3], w1.w, q1);
            q0 += __shfl_xor(q0, 16);
            q0 += __shfl_xor(q0, 32);
            q1 += __shfl_xor(q1, 16);
            q1 += __shfl_xor(q1, 32);
            dwv[f][0] = q0;
            dwv[f][1] = q1;
        }
        if (l < 16) {
#pragma unroll
            for (int f = 0; f < 6; ++f) {
                const int c = f * 16 + l;
                __hip_bfloat162 pk;
                pk.x = __float2bfloat16(dwv[f][0] + dw_b[2 * c + 0]);
                pk.y = __float2bfloat16(dwv[f][1] + dw_b[2 * c + 1]);
                *reinterpret_cast<__hip_bfloat162*>(dw_out + (long)gp * 192 +
                                                    2 * c) = pk;
            }
        }
    };

    process(g0, pl00, pl01, pl02, ax0, fg0);
    process(g1, pl10, pl11, pl12, ax1, fg1);
}

extern "C" void kernel_launch(void* const* d_in, const int* in_sizes, int n_in,
                              void* d_out, int out_size, void* d_ws,
                              size_t ws_size, hipStream_t stream) {
    const float* rep_pts = (const float*)d_in[0];
    const float* pts = (const float*)d_in[1];
    const float* fts = (const float*)d_in[2];
    const int* pts_idx = (const int*)d_in[3];
    const float* dense_W = (const float*)d_in[4];
    const float* dense_b = (const float*)d_in[5];
    const float* dense_g = (const float*)d_in[6];
    const float* dense_bt = (const float*)d_in[7];
    const float* d1_W = (const float*)d_in[8];
    const float* d1_b = (const float*)d_in[9];
    const float* d1_g = (const float*)d_in[10];
    const float* d1_bt = (const float*)d_in[11];
    const float* d2_W = (const float*)d_in[12];
    const float* d2_b = (const float*)d_in[13];
    const float* d2_g = (const float*)d_in[14];
    const float* d2_bt = (const float*)d_in[15];
    const float* xt_cW = (const float*)d_in[16];
    const float* xt_cb = (const float*)d_in[17];
    const float* xt_d1W = (const float*)d_in[18];
    const float* xt_d1b = (const float*)d_in[19];
    const float* xt_d2W = (const float*)d_in[20];
    const float* xt_d2b = (const float*)d_in[21];
    const float* dw_W = (const float*)d_in[22];
    const float* dw_b = (const float*)d_in[23];
    const float* pw_W = (const float*)d_in[24];
    const float* pw_b = (const float*)d_in[25];
    const float* sep_g = (const float*)d_in[26];
    const float* sep_bt = (const float*)d_in[27];

    float* ws = (float*)d_ws;
    __hip_bfloat16* fts_lB = (__hip_bfloat16*)ws;              // 8388608 bf16
    __hip_bfloat16* X2Bb = (__hip_bfloat16*)(ws + 8388608);    // 8388608 bf16
    __hip_bfloat16* XcB = (__hip_bfloat16*)(ws + 16777216);    // 8388608 bf16
    __hip_bfloat16* dwB = (__hip_bfloat16*)(ws + 16777216);    // overlays XcB
    __hip_bfloat16* X1B = (__hip_bfloat16*)(ws + 20971520);    // 8388608 bf16
    float* pl = ws + 25165824;                                 // 1572864 f32
    __hip_bfloat16* d1Wt = (__hip_bfloat16*)(ws + 26738688);   // 65536 bf16
    __hip_bfloat16* d2Wt = (__hip_bfloat16*)(ws + 26771456);   // 65536 bf16
    __hip_bfloat16* pwWt = (__hip_bfloat16*)(ws + 26804224);   // 24576 bf16
    __hip_bfloat16* d2pWt = (__hip_bfloat16*)(ws + 26816512);  // 1024 bf16

    // 0) weight convert+transpose to bf16
    convert_weights<<<256, 256, 0, stream>>>(xt_d1W, xt_d2W, pw_W, d2_W, d1Wt,
                                             d2Wt, pwWt, d2pWt);

    // 1) fts_l = bn(elu(fts @ dense_W + b))  f32 GEMM -> bf16 out
    gemm_bias_act<1, 1, 1><<<dim3(2048, 1), 256, 0, stream>>>(
        fts, dense_W, dense_b, dense_g, dense_bt, fts_lB, 64, 64);

    // 2) pts_local + Xc (bf16)
    setup_kernel<<<2048, 256, 0, stream>>>(rep_pts, pts, pts_idx, xt_cW, xt_cb,
                                           pl, XcB);

    // 3) X1 = elu(Xc @ xt_d1W + b)  bf16 MFMA -> bf16
    mfma_gemm<1, 0, 1><<<dim3(256, 2), 256, 0, stream>>>(
        XcB, d1Wt, xt_d1b, nullptr, nullptr, X1B, 256, 256);

    // 4) X2 = X1 @ xt_d2W + b  bf16 MFMA -> bf16
    mfma_gemm<0, 0, 1><<<dim3(256, 2), 256, 0, stream>>>(
        X1B, d2Wt, xt_d2b, nullptr, nullptr, X2Bb, 256, 256);

    // 5) lifted/gather/fts_X/dw -> dwB (bf16), 2 pts/wave, SMEM-free body
    final_stage_kernel<<<4096, 256, 0, stream>>>(
        X2Bb, pl, pts_idx, fts_lB, d1_W, d1_b, d1_g, d1_bt, d2pWt, d2_b, d2_g,
        d2_bt, dw_W, dw_b, dwB);

    // 6) out = bn(elu(dw @ pw_W + pw_b))  bf16 MFMA -> f32
    mfma_gemm<1, 1, 0><<<dim3(256, 1), 256, 0, stream>>>(
        dwB, pwWt, pw_b, sep_g, sep_bt, d_out, 192, 128);
}

// Round 12
// 188.577 us; speedup vs baseline: 1.0606x; 1.0606x over previous
//
#include <hip/hip_runtime.h>
#include <hip/hip_bf16.h>

#define RS 0.9999950000374998f  // 1/sqrt(1+1e-5)

__device__ __forceinline__ float eluf(float x) {
    return x > 0.0f ? x : __expf(x) - 1.0f;
}

typedef __attribute__((ext_vector_type(8))) __bf16 bf16x8;
typedef __attribute__((ext_vector_type(4))) float f32x4;
typedef __attribute__((ext_vector_type(4))) unsigned int u32x4;

// ---------------------------------------------------------------------------
// f32-input tiled GEMM (fts_l). OUTB=1 -> bf16 output.
// ---------------------------------------------------------------------------
template <int ACT, int BN, int OUTB>
__global__ __launch_bounds__(256) void gemm_bias_act(
    const float* __restrict__ A, const float* __restrict__ W,
    const float* __restrict__ bias, const float* __restrict__ gamma,
    const float* __restrict__ beta, void* __restrict__ outp,
    int Kdim, int Ncols) {
    __shared__ float As[16][64];
    __shared__ float Bs[16][64];
    const int tid = threadIdx.x;
    const int tx = tid & 15, ty = tid >> 4;
    const long row0 = (long)blockIdx.x * 64;
    const int col0 = blockIdx.y * 64;
    const int rA = tid >> 2, kqA = (tid & 3) << 2;
    const int kkB = tid >> 4, cqB = (tid & 15) << 2;
    float acc[4][4] = {};
    for (int k0 = 0; k0 < Kdim; k0 += 16) {
        const float4 av = *reinterpret_cast<const float4*>(
            A + (row0 + rA) * (long)Kdim + (k0 + kqA));
        const float4 bv = *reinterpret_cast<const float4*>(
            W + (long)(k0 + kkB) * Ncols + (col0 + cqB));
        As[kqA + 0][rA] = av.x;
        As[kqA + 1][rA] = av.y;
        As[kqA + 2][rA] = av.z;
        As[kqA + 3][rA] = av.w;
        *reinterpret_cast<float4*>(&Bs[kkB][cqB]) = bv;
        __syncthreads();
#pragma unroll
        for (int kk = 0; kk < 16; ++kk) {
            float a[4], b[4];
#pragma unroll
            for (int i = 0; i < 4; ++i) a[i] = As[kk][ty * 4 + i];
#pragma unroll
            for (int j = 0; j < 4; ++j) b[j] = Bs[kk][tx * 4 + j];
#pragma unroll
            for (int i = 0; i < 4; ++i)
#pragma unroll
                for (int j = 0; j < 4; ++j) acc[i][j] = fmaf(a[i], b[j], acc[i][j]);
        }
        __syncthreads();
    }
#pragma unroll
    for (int j = 0; j < 4; ++j) {
        const int col = col0 + tx * 4 + j;
        const float bb = bias[col];
        const float gs = BN ? gamma[col] * RS : 0.0f;
        const float bt = BN ? beta[col] : 0.0f;
#pragma unroll
        for (int i = 0; i < 4; ++i) {
            const long row = row0 + ty * 4 + i;
            float v = acc[i][j] + bb;
            if (ACT) v = eluf(v);
            if (BN) v = v * gs + bt;
            if (OUTB)
                reinterpret_cast<__hip_bfloat16*>(outp)[row * Ncols + col] =
                    __float2bfloat16(v);
            else
                reinterpret_cast<float*>(outp)[row * Ncols + col] = v;
        }
    }
}

// ---------------------------------------------------------------------------
// Weight conversion to bf16-transposed forms. One-shot, tiny.
// ---------------------------------------------------------------------------
__global__ __launch_bounds__(256) void convert_weights(
    const float* __restrict__ d1W, const float* __restrict__ d2W,
    const float* __restrict__ pwW, const float* __restrict__ d2Ws,
    __hip_bfloat16* __restrict__ d1Wt, __hip_bfloat16* __restrict__ d2Wt,
    __hip_bfloat16* __restrict__ pwWt, __hip_bfloat16* __restrict__ d2pWt) {
    const int t = blockIdx.x * 256 + threadIdx.x;
    if (t < 65536) {
        const int k = t >> 8, n = t & 255;
        d1Wt[n * 256 + k] = __float2bfloat16(d1W[t]);
        d2Wt[n * 256 + k] = __float2bfloat16(d2W[t]);
    }
    if (t < 24576) {
        const int k = t >> 7, n = t & 127;
        pwWt[n * 192 + k] = __float2bfloat16(pwW[t]);
    }
    if (t < 1024) {
        const int q = t >> 5, c = t & 31;
        d2pWt[c * 32 + q] = __float2bfloat16(d2Ws[t]);
    }
}

// ---------------------------------------------------------------------------
// bf16 MFMA GEMM (R7 winner): out = post(A @ Wt^T + bias), Wt pre-transposed.
// Tile 128x128, BK=32, 4 waves.
// ---------------------------------------------------------------------------
template <int ACT, int BN_, int OUTB>
__global__ __launch_bounds__(256) void mfma_gemm(
    const __hip_bfloat16* __restrict__ A, const __hip_bfloat16* __restrict__ Wt,
    const float* __restrict__ bias, const float* __restrict__ gamma,
    const float* __restrict__ beta, void* __restrict__ outp, int K, int Ncols) {
    __shared__ __bf16 As[128][40];
    __shared__ __bf16 Bs[128][40];
    const int tid = threadIdx.x;
    const int w = tid >> 6, l = tid & 63;
    const int wm = w >> 1, wn = w & 1;
    const long row0 = (long)blockIdx.x * 128;
    const int col0 = blockIdx.y * 128;
    const int sr = tid >> 1, sh = tid & 1;
    const int fr = l & 15, kg = (l >> 4) * 8;
    f32x4 acc[4][4] = {};
    const __hip_bfloat16* __restrict__ ap = A + (row0 + sr) * (long)K + sh * 16;
    const __hip_bfloat16* __restrict__ bp =
        Wt + (long)(col0 + sr) * K + sh * 16;
    for (int k0 = 0; k0 < K; k0 += 32) {
        const uint4 av0 = *reinterpret_cast<const uint4*>(ap + k0);
        const uint4 av1 = *reinterpret_cast<const uint4*>(ap + k0 + 8);
        const uint4 bv0 = *reinterpret_cast<const uint4*>(bp + k0);
        const uint4 bv1 = *reinterpret_cast<const uint4*>(bp + k0 + 8);
        *reinterpret_cast<uint4*>(&As[sr][sh * 16]) = av0;
        *reinterpret_cast<uint4*>(&As[sr][sh * 16 + 8]) = av1;
        *reinterpret_cast<uint4*>(&Bs[sr][sh * 16]) = bv0;
        *reinterpret_cast<uint4*>(&Bs[sr][sh * 16 + 8]) = bv1;
        __syncthreads();
        bf16x8 af[4], bfv[4];
#pragma unroll
        for (int mt = 0; mt < 4; ++mt)
            af[mt] =
                *reinterpret_cast<const bf16x8*>(&As[wm * 64 + mt * 16 + fr][kg]);
#pragma unroll
        for (int nt = 0; nt < 4; ++nt)
            bfv[nt] =
                *reinterpret_cast<const bf16x8*>(&Bs[wn * 64 + nt * 16 + fr][kg]);
#pragma unroll
        for (int mt = 0; mt < 4; ++mt)
#pragma unroll
            for (int nt = 0; nt < 4; ++nt)
                acc[mt][nt] = __builtin_amdgcn_mfma_f32_16x16x32_bf16(
                    af[mt], bfv[nt], acc[mt][nt], 0, 0, 0);
        __syncthreads();
    }
    const int rg = (l >> 4) * 4;
#pragma unroll
    for (int nt = 0; nt < 4; ++nt) {
        const int col = col0 + wn * 64 + nt * 16 + fr;
        const float bb = bias[col];
        const float gs = BN_ ? gamma[col] * RS : 0.0f;
        const float bt = BN_ ? beta[col] : 0.0f;
#pragma unroll
        for (int mt = 0; mt < 4; ++mt) {
#pragma unroll
            for (int r = 0; r < 4; ++r) {
                const long row = row0 + wm * 64 + mt * 16 + rg + r;
                float v = acc[mt][nt][r] + bb;
                if (ACT) v = eluf(v);
                if (BN_) v = v * gs + bt;
                if (OUTB)
                    reinterpret_cast<__hip_bfloat16*>(outp)[row * Ncols + col] =
                        __float2bfloat16(v);
                else
                    reinterpret_cast<float*>(outp)[row * Ncols + col] = v;
            }
        }
    }
}

// ---------------------------------------------------------------------------
// Setup: pts_local (f32 store) + Xc (bf16 store). 16 pts/block, grid 2048.
// ---------------------------------------------------------------------------
__global__ __launch_bounds__(256) void setup_kernel(
    const float* __restrict__ rep_pts, const float* __restrict__ pts,
    const int* __restrict__ pts_idx, const float* __restrict__ xt_cW,
    const float* __restrict__ xt_cb, float* __restrict__ pts_local,
    __hip_bfloat16* __restrict__ Xc) {
    __shared__ float cwT[48][256];
    __shared__ float pl2[16][48];
    __shared__ float cb_s[256];
    const int tid = threadIdx.x;
    const long gp0 = (long)blockIdx.x * 16;
#pragma unroll
    for (int i = 0; i < 48; ++i) {
        const int e = i * 256 + tid;
        const int o = e / 48, r = e - o * 48;
        cwT[r][o] = xt_cW[e];
    }
    cb_s[tid] = xt_cb[tid];
    {
        const int pt = tid >> 4, k = tid & 15;
        const long gp = gp0 + pt;
        const int n = (int)(gp >> 11);
        const int idx = pts_idx[gp * 32 + 2 * k];
        const float* ps = pts + ((long)n * 8192 + idx) * 3;
        const float* rs = rep_pts + gp * 3;
        float* plo = pts_local + gp * 48 + k * 3;
#pragma unroll
        for (int d = 0; d < 3; ++d) {
            const float v = ps[d] - rs[d];
            pl2[pt][d * 16 + k] = v;
            plo[d] = v;
        }
    }
    __syncthreads();
    const int o = tid;
    for (int pt = 0; pt < 16; ++pt) {
        float acc = cb_s[o];
#pragma unroll
        for (int i = 0; i < 48; ++i) acc = fmaf(pl2[pt][i], cwT[i][o], acc);
        Xc[(gp0 + pt) * 256 + o] = __float2bfloat16(eluf(acc));
    }
}

// ---------------------------------------------------------------------------
// Final per-point stage v10: R9 winning body (1 pt/wave, s_load idx, bf16
// gather) but 1024-thread blocks = 16 waves/dispatch, grid 2048.
// Rationale: R9 showed 37% occupancy with no static limit (VGPR 52, LDS ok)
// -> dispatch granularity suspected; one dispatch now delivers 16 waves.
// fcat [16][96][24] = 73.7 KB -> 2 blocks/CU = 32 waves/CU theoretical.
// XCD swizzle bijective (2048 % 8 == 0): XCD x gets 256 contiguous blocks
// = 4096 points = 2 batches (bf16 fts_l slices fit 4 MB L2).
// No barriers (all LDS wave-private; in-wave DS ordering).
// NOTE: no 2nd __launch_bounds__ arg (R4: clamp -> spill).
// ---------------------------------------------------------------------------
__global__ __launch_bounds__(1024) void final_stage_kernel(
    const __hip_bfloat16* __restrict__ X2B,  // [32768][256] bf16
    const float* __restrict__ pts_local,     // [32768][48] (k*3+d)
    const int* __restrict__ pts_idx,
    const __hip_bfloat16* __restrict__ fts_lB,  // [131072][64] bf16
    const float* __restrict__ d1_W, const float* __restrict__ d1_b,
    const float* __restrict__ d1_g, const float* __restrict__ d1_bt,
    const __hip_bfloat16* __restrict__ d2pWt,  // [32 c][32 q] bf16
    const float* __restrict__ d2_b, const float* __restrict__ d2_g,
    const float* __restrict__ d2_bt, const float* __restrict__ dw_W,
    const float* __restrict__ dw_b,
    __hip_bfloat16* __restrict__ dw_out)  // [32768][192] bf16
{
    __shared__ __bf16 fcat[16][96][24];  // wave-private

    const int tid = threadIdx.x;
    const int w = tid >> 6, l = tid & 63;
    const int obid = blockIdx.x;
    const int bid = (obid & 7) * 256 + (obid >> 3);  // bijective, 2048%8==0
    const int gp = bid * 16 + w;
    const int ugp = __builtin_amdgcn_readfirstlane(gp);  // wave-uniform
    const int n = ugp >> 11;
    const int fr = l & 15;        // fragment row/col within 16
    const int kg = (l >> 4) * 8;  // k-chunk start: 0,8,16,24
    const int kk = kg & 15;       // wrapped: 0,8
    const unsigned msk = (l < 32) ? 0xFFFFFFFFu : 0u;
    const int rg4 = (l >> 4) * 4;
    const int colg = (l < 32) ? (32 + l) : (l - 32);
    const __hip_bfloat16* __restrict__ fbase =
        fts_lB + (long)n * 8192 * 64 + colg;

    // ---- fts gather: lane owns bf16 col colg, 16 rows (idx via s_load) ----
    const int* __restrict__ ip = pts_idx + (long)ugp * 32;
    unsigned fg[16];
#pragma unroll
    for (int j = 0; j < 16; ++j)
        fg[j] = *reinterpret_cast<const unsigned short*>(
            &fbase[(long)ip[2 * j] * 64]);

    // ---- pts_local (lane reads its own row fr's 3 coords) ----
    const float* __restrict__ pp = pts_local + (long)ugp * 48 + fr * 3;
    const float plA0 = pp[0], plA1 = pp[1], plA2 = pp[2];

    // ---- l0 row-owner into A-frag: lane = row fr, k-cols kg..kg+7 ----
    bf16x8 a_l0;
    {
#pragma unroll
        for (int jj = 0; jj < 8; ++jj) {
            const int q = kg + jj;
            float a = d1_b[q];
            a = fmaf(plA0, d1_W[q], a);
            a = fmaf(plA1, d1_W[32 + q], a);
            a = fmaf(plA2, d1_W[64 + q], a);
            a = eluf(a);
            a = a * (d1_g[q] * RS) + d1_bt[q];
            a_l0[jj] = (__bf16)a;
        }
    }

    // ---- lifted = l0 @ d2_W via 2 MFMA (K=32 exact) -> fcat cols 0..31 ----
    {
        const bf16x8 b0 =
            *reinterpret_cast<const bf16x8*>(d2pWt + (0 + fr) * 32 + kg);
        const bf16x8 b1 =
            *reinterpret_cast<const bf16x8*>(d2pWt + (16 + fr) * 32 + kg);
        f32x4 lif0 = {}, lif1 = {};
        lif0 = __builtin_amdgcn_mfma_f32_16x16x32_bf16(a_l0, b0, lif0, 0, 0, 0);
        lif1 = __builtin_amdgcn_mfma_f32_16x16x32_bf16(a_l0, b1, lif1, 0, 0, 0);
#pragma unroll
        for (int f = 0; f < 2; ++f) {
            const int c = f * 16 + fr;
            const float bb = d2_b[c], gs = d2_g[c] * RS, bt = d2_bt[c];
            const f32x4 dd = f ? lif1 : lif0;
            unsigned short pk[4];
#pragma unroll
            for (int r = 0; r < 4; ++r) {
                float v = dd[r] + bb;
                v = eluf(v) * gs + bt;
                const __bf16 h = (__bf16)v;
                pk[r] = *reinterpret_cast<const unsigned short*>(&h);
            }
            *reinterpret_cast<uint2*>(&fcat[w][c][rg4]) =
                make_uint2((unsigned)pk[0] | ((unsigned)pk[1] << 16),
                           (unsigned)pk[2] | ((unsigned)pk[3] << 16));
        }
    }

    // ---- fg (bf16 bits) -> fcat[32+colg][0..15] (2 x ds_write_b128) ----
    {
        const uint4 lo = make_uint4(fg[0] | (fg[1] << 16), fg[2] | (fg[3] << 16),
                                    fg[4] | (fg[5] << 16), fg[6] | (fg[7] << 16));
        const uint4 hi =
            make_uint4(fg[8] | (fg[9] << 16), fg[10] | (fg[11] << 16),
                       fg[12] | (fg[13] << 16), fg[14] | (fg[15] << 16));
        *reinterpret_cast<uint4*>(&fcat[w][32 + colg][0]) = lo;
        *reinterpret_cast<uint4*>(&fcat[w][32 + colg][8]) = hi;
    }

    // ---- A-frag: X row fr, k=kk..kk+7 from bf16 X2 (zero for lanes>=32) ----
    u32x4 axu =
        *reinterpret_cast<const u32x4*>(X2B + (long)ugp * 256 + fr * 16 + kk);
    axu &= msk;
    const bf16x8 ax = *reinterpret_cast<const bf16x8*>(&axu);

    // ---- fts_X: 6 B-frags from fcat + 6 MFMA ----
    f32x4 acc[6];
#pragma unroll
    for (int f = 0; f < 6; ++f) acc[f] = (f32x4){};
#pragma unroll
    for (int f = 0; f < 6; ++f) {
        u32x4 bu = *reinterpret_cast<const u32x4*>(&fcat[w][f * 16 + fr][kk]);
        bu &= msk;  // zero k>=16 (also kills uninit-LDS NaN)
        const bf16x8 bf = *reinterpret_cast<const bf16x8*>(&bu);
        acc[f] = __builtin_amdgcn_mfma_f32_16x16x32_bf16(ax, bf, acc[f], 0, 0, 0);
    }

    // ---- dw: partials over rows rg4..rg4+3, butterfly over lane groups ----
    float dwv[6][2];
#pragma unroll
    for (int f = 0; f < 6; ++f) {
        const int c = f * 16 + fr;
        const float4 w0 = *reinterpret_cast<const float4*>(dw_W + c * 32 + rg4);
        const float4 w1 =
            *reinterpret_cast<const float4*>(dw_W + c * 32 + 16 + rg4);
        float p0 = acc[f][0] * w0.x;
        p0 = fmaf(acc[f][1], w0.y, p0);
        p0 = fmaf(acc[f][2], w0.z, p0);
        p0 = fmaf(acc[f][3], w0.w, p0);
        float p1 = acc[f][0] * w1.x;
        p1 = fmaf(acc[f][1], w1.y, p1);
        p1 = fmaf(acc[f][2], w1.z, p1);
        p1 = fmaf(acc[f][3], w1.w, p1);
        p0 += __shfl_xor(p0, 16);
        p0 += __shfl_xor(p0, 32);
        p1 += __shfl_xor(p1, 16);
        p1 += __shfl_xor(p1, 32);
        dwv[f][0] = p0;
        dwv[f][1] = p1;
    }
    if (l < 16) {
#pragma unroll
        for (int f = 0; f < 6; ++f) {
            const int c = f * 16 + l;
            __hip_bfloat162 pk;
            pk.x = __float2bfloat16(dwv[f][0] + dw_b[2 * c + 0]);
            pk.y = __float2bfloat16(dwv[f][1] + dw_b[2 * c + 1]);
            *reinterpret_cast<__hip_bfloat162*>(dw_out + (long)gp * 192 +
                                                2 * c) = pk;
        }
    }
}

extern "C" void kernel_launch(void* const* d_in, const int* in_sizes, int n_in,
                              void* d_out, int out_size, void* d_ws,
                              size_t ws_size, hipStream_t stream) {
    const float* rep_pts = (const float*)d_in[0];
    const float* pts = (const float*)d_in[1];
    const float* fts = (const float*)d_in[2];
    const int* pts_idx = (const int*)d_in[3];
    const float* dense_W = (const float*)d_in[4];
    const float* dense_b = (const float*)d_in[5];
    const float* dense_g = (const float*)d_in[6];
    const float* dense_bt = (const float*)d_in[7];
    const float* d1_W = (const float*)d_in[8];
    const float* d1_b = (const float*)d_in[9];
    const float* d1_g = (const float*)d_in[10];
    const float* d1_bt = (const float*)d_in[11];
    const float* d2_W = (const float*)d_in[12];
    const float* d2_b = (const float*)d_in[13];
    const float* d2_g = (const float*)d_in[14];
    const float* d2_bt = (const float*)d_in[15];
    const float* xt_cW = (const float*)d_in[16];
    const float* xt_cb = (const float*)d_in[17];
    const float* xt_d1W = (const float*)d_in[18];
    const float* xt_d1b = (const float*)d_in[19];
    const float* xt_d2W = (const float*)d_in[20];
    const float* xt_d2b = (const float*)d_in[21];
    const float* dw_W = (const float*)d_in[22];
    const float* dw_b = (const float*)d_in[23];
    const float* pw_W = (const float*)d_in[24];
    const float* pw_b = (const float*)d_in[25];
    const float* sep_g = (const float*)d_in[26];
    const float* sep_bt = (const float*)d_in[27];

    float* ws = (float*)d_ws;
    __hip_bfloat16* fts_lB = (__hip_bfloat16*)ws;              // 8388608 bf16
    __hip_bfloat16* X2Bb = (__hip_bfloat16*)(ws + 8388608);    // 8388608 bf16
    __hip_bfloat16* XcB = (__hip_bfloat16*)(ws + 16777216);    // 8388608 bf16
    __hip_bfloat16* dwB = (__hip_bfloat16*)(ws + 16777216);    // overlays XcB
    __hip_bfloat16* X1B = (__hip_bfloat16*)(ws + 20971520);    // 8388608 bf16
    float* pl = ws + 25165824;                                 // 1572864 f32
    __hip_bfloat16* d1Wt = (__hip_bfloat16*)(ws + 26738688);   // 65536 bf16
    __hip_bfloat16* d2Wt = (__hip_bfloat16*)(ws + 26771456);   // 65536 bf16
    __hip_bfloat16* pwWt = (__hip_bfloat16*)(ws + 26804224);   // 24576 bf16
    __hip_bfloat16* d2pWt = (__hip_bfloat16*)(ws + 26816512);  // 1024 bf16

    // 0) weight convert+transpose to bf16
    convert_weights<<<256, 256, 0, stream>>>(xt_d1W, xt_d2W, pw_W, d2_W, d1Wt,
                                             d2Wt, pwWt, d2pWt);

    // 1) fts_l = bn(elu(fts @ dense_W + b))  f32 GEMM -> bf16 out
    gemm_bias_act<1, 1, 1><<<dim3(2048, 1), 256, 0, stream>>>(
        fts, dense_W, dense_b, dense_g, dense_bt, fts_lB, 64, 64);

    // 2) pts_local + Xc (bf16)
    setup_kernel<<<2048, 256, 0, stream>>>(rep_pts, pts, pts_idx, xt_cW, xt_cb,
                                           pl, XcB);

    // 3) X1 = elu(Xc @ xt_d1W + b)  bf16 MFMA -> bf16
    mfma_gemm<1, 0, 1><<<dim3(256, 2), 256, 0, stream>>>(
        XcB, d1Wt, xt_d1b, nullptr, nullptr, X1B, 256, 256);

    // 4) X2 = X1 @ xt_d2W + b  bf16 MFMA -> bf16
    mfma_gemm<0, 0, 1><<<dim3(256, 2), 256, 0, stream>>>(
        X1B, d2Wt, xt_d2b, nullptr, nullptr, X2Bb, 256, 256);

    // 5) lifted/gather/fts_X/dw -> dwB (bf16); 16 waves/block, 1 pt/wave
    final_stage_kernel<<<2048, 1024, 0, stream>>>(
        X2Bb, pl, pts_idx, fts_lB, d1_W, d1_b, d1_g, d1_bt, d2pWt, d2_b, d2_g,
        d2_bt, dw_W, dw_b, dwB);

    // 6) out = bn(elu(dw @ pw_W + pw_b))  bf16 MFMA -> f32
    mfma_gemm<1, 1, 0><<<dim3(256, 1), 256, 0, stream>>>(
        dwB, pwWt, pw_b, sep_g, sep_bt, d_out, 192, 128);
}

// Round 13
// 154.707 us; speedup vs baseline: 1.2928x; 1.2189x over previous
//
#include <hip/hip_runtime.h>
#include <hip/hip_bf16.h>

#define RS 0.9999950000374998f  // 1/sqrt(1+1e-5)

__device__ __forceinline__ float eluf(float x) {
    return x > 0.0f ? x : __expf(x) - 1.0f;
}

typedef __attribute__((ext_vector_type(8))) __bf16 bf16x8;
typedef __attribute__((ext_vector_type(4))) float f32x4;
typedef __attribute__((ext_vector_type(4))) unsigned int u32x4;

// ---------------------------------------------------------------------------
// Weight conversion to bf16-transposed forms. One-shot, tiny. 65536 threads.
//   d1Wt/d2Wt [256][256]<-[K][N];  pwWt [128][192];  d2pWt [32][32];
//   denseWt [64][64];  cWt [256][64] (xt_cW [o][d][k] -> [o][d*16+k], pad 0)
// ---------------------------------------------------------------------------
__global__ __launch_bounds__(256) void convert_weights(
    const float* __restrict__ d1W, const float* __restrict__ d2W,
    const float* __restrict__ pwW, const float* __restrict__ d2Ws,
    const float* __restrict__ denseW, const float* __restrict__ cW,
    __hip_bfloat16* __restrict__ d1Wt, __hip_bfloat16* __restrict__ d2Wt,
    __hip_bfloat16* __restrict__ pwWt, __hip_bfloat16* __restrict__ d2pWt,
    __hip_bfloat16* __restrict__ denseWt, __hip_bfloat16* __restrict__ cWt) {
    const int t = blockIdx.x * 256 + threadIdx.x;
    if (t < 65536) {
        const int k = t >> 8, n = t & 255;
        d1Wt[n * 256 + k] = __float2bfloat16(d1W[t]);
        d2Wt[n * 256 + k] = __float2bfloat16(d2W[t]);
    }
    if (t < 24576) {
        const int k = t >> 7, n = t & 127;
        pwWt[n * 192 + k] = __float2bfloat16(pwW[t]);
    }
    if (t < 1024) {
        const int q = t >> 5, c = t & 31;
        d2pWt[c * 32 + q] = __float2bfloat16(d2Ws[t]);
    }
    if (t < 4096) {
        const int k = t >> 6, n = t & 63;
        denseWt[n * 64 + k] = __float2bfloat16(denseW[t]);
    }
    if (t < 16384) {
        const int o = t >> 6, kq = t & 63;
        cWt[t] = (kq < 48) ? __float2bfloat16(cW[o * 48 + kq])
                           : __float2bfloat16(0.0f);
    }
}

// ---------------------------------------------------------------------------
// Gather: pts_local f32 [32768][48] (k*3+d) + PLB bf16 [32768][64] (d*16+k,
// cols 48-63 zero) + grid-stride fts f32->bf16 cast. 16 pts/block, grid 2048.
// ---------------------------------------------------------------------------
__global__ __launch_bounds__(256) void gather_kernel(
    const float* __restrict__ rep_pts, const float* __restrict__ pts,
    const int* __restrict__ pts_idx, const float* __restrict__ fts,
    float* __restrict__ pts_local, __hip_bfloat16* __restrict__ PLB,
    __hip_bfloat16* __restrict__ ftsB) {
    const int tid = threadIdx.x;
    const long gp0 = (long)blockIdx.x * 16;
    const int pt = tid >> 4, k = tid & 15;
    const long gp = gp0 + pt;
    const int n = (int)(gp >> 11);
    const int idx = pts_idx[gp * 32 + 2 * k];
    const float* ps = pts + ((long)n * 8192 + idx) * 3;
    const float* rs = rep_pts + gp * 3;
#pragma unroll
    for (int d = 0; d < 3; ++d) {
        const float v = ps[d] - rs[d];
        pts_local[gp * 48 + k * 3 + d] = v;
        PLB[gp * 64 + d * 16 + k] = __float2bfloat16(v);
    }
    PLB[gp * 64 + 48 + k] = __float2bfloat16(0.0f);
    // fts cast: 8388608 f32 = 2097152 float4 over 524288 threads (4 iters)
    for (int e = blockIdx.x * 256 + tid; e < 2097152; e += 524288) {
        const float4 fv = reinterpret_cast<const float4*>(fts)[e];
        unsigned short p0, p1, p2, p3;
        __bf16 h;
        h = (__bf16)fv.x; p0 = *reinterpret_cast<unsigned short*>(&h);
        h = (__bf16)fv.y; p1 = *reinterpret_cast<unsigned short*>(&h);
        h = (__bf16)fv.z; p2 = *reinterpret_cast<unsigned short*>(&h);
        h = (__bf16)fv.w; p3 = *reinterpret_cast<unsigned short*>(&h);
        reinterpret_cast<uint2*>(ftsB)[e] =
            make_uint2((unsigned)p0 | ((unsigned)p1 << 16),
                       (unsigned)p2 | ((unsigned)p3 << 16));
    }
}

// ---------------------------------------------------------------------------
// bf16 MFMA GEMM: out = post(A @ Wt^T + bias), Wt pre-transposed [N][K].
// TN=128: tile 128x128, 4 waves in 2x2 (each 64x64).
// TN=64 : tile 128x64,  4 waves stacked (each 32x64).
// BK=32. M mult of 128, Ncols mult of TN, K mult of 32.
// ---------------------------------------------------------------------------
template <int TN, int ACT, int BN_, int OUTB>
__global__ __launch_bounds__(256) void mfma_gemm(
    const __hip_bfloat16* __restrict__ A, const __hip_bfloat16* __restrict__ Wt,
    const float* __restrict__ bias, const float* __restrict__ gamma,
    const float* __restrict__ beta, void* __restrict__ outp, int K, int Ncols) {
    constexpr int MT = (TN == 128) ? 4 : 2;  // row frags per wave
    constexpr int RB = MT * 16;              // wave row-block
    __shared__ __bf16 As[128][40];
    __shared__ __bf16 Bs[TN][40];
    const int tid = threadIdx.x;
    const int w = tid >> 6, l = tid & 63;
    const int wm = (TN == 128) ? (w >> 1) : w;
    const int wn = (TN == 128) ? (w & 1) : 0;
    const long row0 = (long)blockIdx.x * 128;
    const int col0 = blockIdx.y * TN;
    const int sr = tid >> 1, sh = tid & 1;
    const int fr = l & 15, kg = (l >> 4) * 8;
    f32x4 acc[MT][4] = {};
    const __hip_bfloat16* __restrict__ ap = A + (row0 + sr) * (long)K + sh * 16;
    const __hip_bfloat16* __restrict__ bp =
        Wt + (long)(col0 + (TN == 128 ? sr : (sr & 63))) * K + sh * 16;
    for (int k0 = 0; k0 < K; k0 += 32) {
        const uint4 av0 = *reinterpret_cast<const uint4*>(ap + k0);
        const uint4 av1 = *reinterpret_cast<const uint4*>(ap + k0 + 8);
        *reinterpret_cast<uint4*>(&As[sr][sh * 16]) = av0;
        *reinterpret_cast<uint4*>(&As[sr][sh * 16 + 8]) = av1;
        if (TN == 128 || tid < 128) {
            const uint4 bv0 = *reinterpret_cast<const uint4*>(bp + k0);
            const uint4 bv1 = *reinterpret_cast<const uint4*>(bp + k0 + 8);
            *reinterpret_cast<uint4*>(&Bs[TN == 128 ? sr : (sr & 63)][sh * 16]) =
                bv0;
            *reinterpret_cast<uint4*>(
                &Bs[TN == 128 ? sr : (sr & 63)][sh * 16 + 8]) = bv1;
        }
        __syncthreads();
        bf16x8 af[MT], bfv[4];
#pragma unroll
        for (int mt = 0; mt < MT; ++mt)
            af[mt] =
                *reinterpret_cast<const bf16x8*>(&As[wm * RB + mt * 16 + fr][kg]);
#pragma unroll
        for (int nt = 0; nt < 4; ++nt)
            bfv[nt] =
                *reinterpret_cast<const bf16x8*>(&Bs[wn * 64 + nt * 16 + fr][kg]);
#pragma unroll
        for (int mt = 0; mt < MT; ++mt)
#pragma unroll
            for (int nt = 0; nt < 4; ++nt)
                acc[mt][nt] = __builtin_amdgcn_mfma_f32_16x16x32_bf16(
                    af[mt], bfv[nt], acc[mt][nt], 0, 0, 0);
        __syncthreads();
    }
    const int rg = (l >> 4) * 4;
#pragma unroll
    for (int nt = 0; nt < 4; ++nt) {
        const int col = col0 + wn * 64 + nt * 16 + fr;
        const float bb = bias[col];
        const float gs = BN_ ? gamma[col] * RS : 0.0f;
        const float bt = BN_ ? beta[col] : 0.0f;
#pragma unroll
        for (int mt = 0; mt < MT; ++mt) {
#pragma unroll
            for (int r = 0; r < 4; ++r) {
                const long row = row0 + wm * RB + mt * 16 + rg + r;
                float v = acc[mt][nt][r] + bb;
                if (ACT) v = eluf(v);
                if (BN_) v = v * gs + bt;
                if (OUTB)
                    reinterpret_cast<__hip_bfloat16*>(outp)[row * Ncols + col] =
                        __float2bfloat16(v);
                else
                    reinterpret_cast<float*>(outp)[row * Ncols + col] = v;
            }
        }
    }
}

// ---------------------------------------------------------------------------
// Final per-point stage (R12/R9 winner, byte-identical): 1 pt/wave, s_load
// idx, bf16 gather; 1024-thread blocks (16 waves), grid 2048, XCD swizzle.
// No barriers (all LDS wave-private). NOTE: no 2nd __launch_bounds__ arg
// (R4: clamp -> spill).
// ---------------------------------------------------------------------------
__global__ __launch_bounds__(1024) void final_stage_kernel(
    const __hip_bfloat16* __restrict__ X2B,  // [32768][256] bf16
    const float* __restrict__ pts_local,     // [32768][48] (k*3+d)
    const int* __restrict__ pts_idx,
    const __hip_bfloat16* __restrict__ fts_lB,  // [131072][64] bf16
    const float* __restrict__ d1_W, const float* __restrict__ d1_b,
    const float* __restrict__ d1_g, const float* __restrict__ d1_bt,
    const __hip_bfloat16* __restrict__ d2pWt,  // [32 c][32 q] bf16
    const float* __restrict__ d2_b, const float* __restrict__ d2_g,
    const float* __restrict__ d2_bt, const float* __restrict__ dw_W,
    const float* __restrict__ dw_b,
    __hip_bfloat16* __restrict__ dw_out)  // [32768][192] bf16
{
    __shared__ __bf16 fcat[16][96][24];  // wave-private

    const int tid = threadIdx.x;
    const int w = tid >> 6, l = tid & 63;
    const int obid = blockIdx.x;
    const int bid = (obid & 7) * 256 + (obid >> 3);  // bijective, 2048%8==0
    const int gp = bid * 16 + w;
    const int ugp = __builtin_amdgcn_readfirstlane(gp);  // wave-uniform
    const int n = ugp >> 11;
    const int fr = l & 15;
    const int kg = (l >> 4) * 8;
    const int kk = kg & 15;
    const unsigned msk = (l < 32) ? 0xFFFFFFFFu : 0u;
    const int rg4 = (l >> 4) * 4;
    const int colg = (l < 32) ? (32 + l) : (l - 32);
    const __hip_bfloat16* __restrict__ fbase =
        fts_lB + (long)n * 8192 * 64 + colg;

    const int* __restrict__ ip = pts_idx + (long)ugp * 32;
    unsigned fg[16];
#pragma unroll
    for (int j = 0; j < 16; ++j)
        fg[j] = *reinterpret_cast<const unsigned short*>(
            &fbase[(long)ip[2 * j] * 64]);

    const float* __restrict__ pp = pts_local + (long)ugp * 48 + fr * 3;
    const float plA0 = pp[0], plA1 = pp[1], plA2 = pp[2];

    bf16x8 a_l0;
    {
#pragma unroll
        for (int jj = 0; jj < 8; ++jj) {
            const int q = kg + jj;
            float a = d1_b[q];
            a = fmaf(plA0, d1_W[q], a);
            a = fmaf(plA1, d1_W[32 + q], a);
            a = fmaf(plA2, d1_W[64 + q], a);
            a = eluf(a);
            a = a * (d1_g[q] * RS) + d1_bt[q];
            a_l0[jj] = (__bf16)a;
        }
    }

    {
        const bf16x8 b0 =
            *reinterpret_cast<const bf16x8*>(d2pWt + (0 + fr) * 32 + kg);
        const bf16x8 b1 =
            *reinterpret_cast<const bf16x8*>(d2pWt + (16 + fr) * 32 + kg);
        f32x4 lif0 = {}, lif1 = {};
        lif0 = __builtin_amdgcn_mfma_f32_16x16x32_bf16(a_l0, b0, lif0, 0, 0, 0);
        lif1 = __builtin_amdgcn_mfma_f32_16x16x32_bf16(a_l0, b1, lif1, 0, 0, 0);
#pragma unroll
        for (int f = 0; f < 2; ++f) {
            const int c = f * 16 + fr;
            const float bb = d2_b[c], gs = d2_g[c] * RS, bt = d2_bt[c];
            const f32x4 dd = f ? lif1 : lif0;
            unsigned short pk[4];
#pragma unroll
            for (int r = 0; r < 4; ++r) {
                float v = dd[r] + bb;
                v = eluf(v) * gs + bt;
                const __bf16 h = (__bf16)v;
                pk[r] = *reinterpret_cast<const unsigned short*>(&h);
            }
            *reinterpret_cast<uint2*>(&fcat[w][c][rg4]) =
                make_uint2((unsigned)pk[0] | ((unsigned)pk[1] << 16),
                           (unsigned)pk[2] | ((unsigned)pk[3] << 16));
        }
    }

    {
        const uint4 lo = make_uint4(fg[0] | (fg[1] << 16), fg[2] | (fg[3] << 16),
                                    fg[4] | (fg[5] << 16), fg[6] | (fg[7] << 16));
        const uint4 hi =
            make_uint4(fg[8] | (fg[9] << 16), fg[10] | (fg[11] << 16),
                       fg[12] | (fg[13] << 16), fg[14] | (fg[15] << 16));
        *reinterpret_cast<uint4*>(&fcat[w][32 + colg][0]) = lo;
        *reinterpret_cast<uint4*>(&fcat[w][32 + colg][8]) = hi;
    }

    u32x4 axu =
        *reinterpret_cast<const u32x4*>(X2B + (long)ugp * 256 + fr * 16 + kk);
    axu &= msk;
    const bf16x8 ax = *reinterpret_cast<const bf16x8*>(&axu);

    f32x4 acc[6];
#pragma unroll
    for (int f = 0; f < 6; ++f) acc[f] = (f32x4){};
#pragma unroll
    for (int f = 0; f < 6; ++f) {
        u32x4 bu = *reinterpret_cast<const u32x4*>(&fcat[w][f * 16 + fr][kk]);
        bu &= msk;  // zero k>=16 (also kills uninit-LDS NaN)
        const bf16x8 bf = *reinterpret_cast<const bf16x8*>(&bu);
        acc[f] = __builtin_amdgcn_mfma_f32_16x16x32_bf16(ax, bf, acc[f], 0, 0, 0);
    }

    float dwv[6][2];
#pragma unroll
    for (int f = 0; f < 6; ++f) {
        const int c = f * 16 + fr;
        const float4 w0 = *reinterpret_cast<const float4*>(dw_W + c * 32 + rg4);
        const float4 w1 =
            *reinterpret_cast<const float4*>(dw_W + c * 32 + 16 + rg4);
        float p0 = acc[f][0] * w0.x;
        p0 = fmaf(acc[f][1], w0.y, p0);
        p0 = fmaf(acc[f][2], w0.z, p0);
        p0 = fmaf(acc[f][3], w0.w, p0);
        float p1 = acc[f][0] * w1.x;
        p1 = fmaf(acc[f][1], w1.y, p1);
        p1 = fmaf(acc[f][2], w1.z, p1);
        p1 = fmaf(acc[f][3], w1.w, p1);
        p0 += __shfl_xor(p0, 16);
        p0 += __shfl_xor(p0, 32);
        p1 += __shfl_xor(p1, 16);
        p1 += __shfl_xor(p1, 32);
        dwv[f][0] = p0;
        dwv[f][1] = p1;
    }
    if (l < 16) {
#pragma unroll
        for (int f = 0; f < 6; ++f) {
            const int c = f * 16 + l;
            __hip_bfloat162 pk;
            pk.x = __float2bfloat16(dwv[f][0] + dw_b[2 * c + 0]);
            pk.y = __float2bfloat16(dwv[f][1] + dw_b[2 * c + 1]);
            *reinterpret_cast<__hip_bfloat162*>(dw_out + (long)gp * 192 +
                                                2 * c) = pk;
        }
    }
}

extern "C" void kernel_launch(void* const* d_in, const int* in_sizes, int n_in,
                              void* d_out, int out_size, void* d_ws,
                              size_t ws_size, hipStream_t stream) {
    const float* rep_pts = (const float*)d_in[0];
    const float* pts = (const float*)d_in[1];
    const float* fts = (const float*)d_in[2];
    const int* pts_idx = (const int*)d_in[3];
    const float* dense_W = (const float*)d_in[4];
    const float* dense_b = (const float*)d_in[5];
    const float* dense_g = (const float*)d_in[6];
    const float* dense_bt = (const float*)d_in[7];
    const float* d1_W = (const float*)d_in[8];
    const float* d1_b = (const float*)d_in[9];
    const float* d1_g = (const float*)d_in[10];
    const float* d1_bt = (const float*)d_in[11];
    const float* d2_W = (const float*)d_in[12];
    const float* d2_b = (const float*)d_in[13];
    const float* d2_g = (const float*)d_in[14];
    const float* d2_bt = (const float*)d_in[15];
    const float* xt_cW = (const float*)d_in[16];
    const float* xt_cb = (const float*)d_in[17];
    const float* xt_d1W = (const float*)d_in[18];
    const float* xt_d1b = (const float*)d_in[19];
    const float* xt_d2W = (const float*)d_in[20];
    const float* xt_d2b = (const float*)d_in[21];
    const float* dw_W = (const float*)d_in[22];
    const float* dw_b = (const float*)d_in[23];
    const float* pw_W = (const float*)d_in[24];
    const float* pw_b = (const float*)d_in[25];
    const float* sep_g = (const float*)d_in[26];
    const float* sep_bt = (const float*)d_in[27];

    float* ws = (float*)d_ws;
    // Overlay plan (stream-ordered lifetimes):
    //   fts_lB  @ ws+0         : bf16 8388608 (written step 3, read by final)
    //   X2Bb    @ ws+8388608   : bf16 8388608
    //   region C@ ws+16777216  : ftsB (gather->fts_l) then XcB (Xc->X1)
    //                            then dwB (final->pw)
    //   region D@ ws+20971520  : PLB (gather->Xc) then X1B (X1->X2)
    //   pl      @ ws+25165824  : f32 1572864
    //   weights @ ws+26738688..
    __hip_bfloat16* fts_lB = (__hip_bfloat16*)ws;
    __hip_bfloat16* X2Bb = (__hip_bfloat16*)(ws + 8388608);
    __hip_bfloat16* ftsB = (__hip_bfloat16*)(ws + 16777216);
    __hip_bfloat16* XcB = (__hip_bfloat16*)(ws + 16777216);
    __hip_bfloat16* dwB = (__hip_bfloat16*)(ws + 16777216);
    __hip_bfloat16* PLB = (__hip_bfloat16*)(ws + 20971520);
    __hip_bfloat16* X1B = (__hip_bfloat16*)(ws + 20971520);
    float* pl = ws + 25165824;
    __hip_bfloat16* d1Wt = (__hip_bfloat16*)(ws + 26738688);   // 65536
    __hip_bfloat16* d2Wt = (__hip_bfloat16*)(ws + 26771456);   // 65536
    __hip_bfloat16* pwWt = (__hip_bfloat16*)(ws + 26804224);   // 24576
    __hip_bfloat16* d2pWt = (__hip_bfloat16*)(ws + 26816512);  // 1024
    __hip_bfloat16* denseWt = (__hip_bfloat16*)(ws + 26817024);  // 4096
    __hip_bfloat16* cWt = (__hip_bfloat16*)(ws + 26819072);      // 16384

    // 0) weight convert+transpose to bf16
    convert_weights<<<256, 256, 0, stream>>>(xt_d1W, xt_d2W, pw_W, d2_W,
                                             dense_W, xt_cW, d1Wt, d2Wt, pwWt,
                                             d2pWt, denseWt, cWt);

    // 1) gather: pts_local + PLB + fts cast
    gather_kernel<<<2048, 256, 0, stream>>>(rep_pts, pts, pts_idx, fts, pl, PLB,
                                            ftsB);

    // 2) fts_l = bn(elu(fts @ dense_W + b))  MFMA TN=64, K=64
    mfma_gemm<64, 1, 1, 1><<<dim3(1024, 1), 256, 0, stream>>>(
        ftsB, denseWt, dense_b, dense_g, dense_bt, fts_lB, 64, 64);

    // 3) Xc = elu(PLB @ cWt^T + cb)  MFMA TN=128, K=64 (overwrites ftsB)
    mfma_gemm<128, 1, 0, 1><<<dim3(256, 2), 256, 0, stream>>>(
        PLB, cWt, xt_cb, nullptr, nullptr, XcB, 64, 256);

    // 4) X1 = elu(Xc @ xt_d1W + b)  MFMA -> bf16 (overwrites PLB)
    mfma_gemm<128, 1, 0, 1><<<dim3(256, 2), 256, 0, stream>>>(
        XcB, d1Wt, xt_d1b, nullptr, nullptr, X1B, 256, 256);

    // 5) X2 = X1 @ xt_d2W + b  MFMA -> bf16
    mfma_gemm<128, 0, 0, 1><<<dim3(256, 2), 256, 0, stream>>>(
        X1B, d2Wt, xt_d2b, nullptr, nullptr, X2Bb, 256, 256);

    // 6) lifted/gather/fts_X/dw -> dwB (overwrites XcB)
    final_stage_kernel<<<2048, 1024, 0, stream>>>(
        X2Bb, pl, pts_idx, fts_lB, d1_W, d1_b, d1_g, d1_bt, d2pWt, d2_b, d2_g,
        d2_bt, dw_W, dw_b, dwB);

    // 7) out = bn(elu(dw @ pw_W + pw_b))  MFMA -> f32
    mfma_gemm<128, 1, 1, 0><<<dim3(256, 1), 256, 0, stream>>>(
        dwB, pwWt, pw_b, sep_g, sep_bt, d_out, 192, 128);
}

// Round 14
// 137.960 us; speedup vs baseline: 1.4497x; 1.1214x over previous
//
#include <hip/hip_runtime.h>
#include <hip/hip_bf16.h>

#define RS 0.9999950000374998f  // 1/sqrt(1+1e-5)

__device__ __forceinline__ float eluf(float x) {
    return x > 0.0f ? x : __expf(x) - 1.0f;
}

typedef __attribute__((ext_vector_type(8))) __bf16 bf16x8;
typedef __attribute__((ext_vector_type(4))) float f32x4;
typedef __attribute__((ext_vector_type(4))) unsigned int u32x4;

// ---------------------------------------------------------------------------
// Weight conversion to bf16-transposed forms. One-shot, tiny. 65536 threads.
// ---------------------------------------------------------------------------
__global__ __launch_bounds__(256) void convert_weights(
    const float* __restrict__ d1W, const float* __restrict__ d2W,
    const float* __restrict__ pwW, const float* __restrict__ d2Ws,
    const float* __restrict__ denseW, const float* __restrict__ cW,
    __hip_bfloat16* __restrict__ d1Wt, __hip_bfloat16* __restrict__ d2Wt,
    __hip_bfloat16* __restrict__ pwWt, __hip_bfloat16* __restrict__ d2pWt,
    __hip_bfloat16* __restrict__ denseWt, __hip_bfloat16* __restrict__ cWt) {
    const int t = blockIdx.x * 256 + threadIdx.x;
    if (t < 65536) {
        const int k = t >> 8, n = t & 255;
        d1Wt[n * 256 + k] = __float2bfloat16(d1W[t]);
        d2Wt[n * 256 + k] = __float2bfloat16(d2W[t]);
    }
    if (t < 24576) {
        const int k = t >> 7, n = t & 127;
        pwWt[n * 192 + k] = __float2bfloat16(pwW[t]);
    }
    if (t < 1024) {
        const int q = t >> 5, c = t & 31;
        d2pWt[c * 32 + q] = __float2bfloat16(d2Ws[t]);
    }
    if (t < 4096) {
        const int k = t >> 6, n = t & 63;
        denseWt[n * 64 + k] = __float2bfloat16(denseW[t]);
    }
    if (t < 16384) {
        const int o = t >> 6, kq = t & 63;
        cWt[t] = (kq < 48) ? __float2bfloat16(cW[o * 48 + kq])
                           : __float2bfloat16(0.0f);
    }
}

// ---------------------------------------------------------------------------
// Gather: pts_local f32 [32768][48] (k*3+d) + PLB bf16 [32768][64] (d*16+k,
// cols 48-63 zero) + grid-stride fts f32->bf16 cast. 16 pts/block, grid 2048.
// ---------------------------------------------------------------------------
__global__ __launch_bounds__(256) void gather_kernel(
    const float* __restrict__ rep_pts, const float* __restrict__ pts,
    const int* __restrict__ pts_idx, const float* __restrict__ fts,
    float* __restrict__ pts_local, __hip_bfloat16* __restrict__ PLB,
    __hip_bfloat16* __restrict__ ftsB) {
    const int tid = threadIdx.x;
    const long gp0 = (long)blockIdx.x * 16;
    const int pt = tid >> 4, k = tid & 15;
    const long gp = gp0 + pt;
    const int n = (int)(gp >> 11);
    const int idx = pts_idx[gp * 32 + 2 * k];
    const float* ps = pts + ((long)n * 8192 + idx) * 3;
    const float* rs = rep_pts + gp * 3;
#pragma unroll
    for (int d = 0; d < 3; ++d) {
        const float v = ps[d] - rs[d];
        pts_local[gp * 48 + k * 3 + d] = v;
        PLB[gp * 64 + d * 16 + k] = __float2bfloat16(v);
    }
    PLB[gp * 64 + 48 + k] = __float2bfloat16(0.0f);
    for (int e = blockIdx.x * 256 + tid; e < 2097152; e += 524288) {
        const float4 fv = reinterpret_cast<const float4*>(fts)[e];
        unsigned short p0, p1, p2, p3;
        __bf16 h;
        h = (__bf16)fv.x; p0 = *reinterpret_cast<unsigned short*>(&h);
        h = (__bf16)fv.y; p1 = *reinterpret_cast<unsigned short*>(&h);
        h = (__bf16)fv.z; p2 = *reinterpret_cast<unsigned short*>(&h);
        h = (__bf16)fv.w; p3 = *reinterpret_cast<unsigned short*>(&h);
        reinterpret_cast<uint2*>(ftsB)[e] =
            make_uint2((unsigned)p0 | ((unsigned)p1 << 16),
                       (unsigned)p2 | ((unsigned)p3 << 16));
    }
}

// ---------------------------------------------------------------------------
// bf16 MFMA GEMM (used for fts_l TN=64 and pw TN=128). Wt pre-transposed.
// ---------------------------------------------------------------------------
template <int TN, int ACT, int BN_, int OUTB>
__global__ __launch_bounds__(256) void mfma_gemm(
    const __hip_bfloat16* __restrict__ A, const __hip_bfloat16* __restrict__ Wt,
    const float* __restrict__ bias, const float* __restrict__ gamma,
    const float* __restrict__ beta, void* __restrict__ outp, int K, int Ncols) {
    constexpr int MT = (TN == 128) ? 4 : 2;
    constexpr int RB = MT * 16;
    __shared__ __bf16 As[128][40];
    __shared__ __bf16 Bs[TN][40];
    const int tid = threadIdx.x;
    const int w = tid >> 6, l = tid & 63;
    const int wm = (TN == 128) ? (w >> 1) : w;
    const int wn = (TN == 128) ? (w & 1) : 0;
    const long row0 = (long)blockIdx.x * 128;
    const int col0 = blockIdx.y * TN;
    const int sr = tid >> 1, sh = tid & 1;
    const int fr = l & 15, kg = (l >> 4) * 8;
    f32x4 acc[MT][4] = {};
    const __hip_bfloat16* __restrict__ ap = A + (row0 + sr) * (long)K + sh * 16;
    const __hip_bfloat16* __restrict__ bp =
        Wt + (long)(col0 + (TN == 128 ? sr : (sr & 63))) * K + sh * 16;
    for (int k0 = 0; k0 < K; k0 += 32) {
        const uint4 av0 = *reinterpret_cast<const uint4*>(ap + k0);
        const uint4 av1 = *reinterpret_cast<const uint4*>(ap + k0 + 8);
        *reinterpret_cast<uint4*>(&As[sr][sh * 16]) = av0;
        *reinterpret_cast<uint4*>(&As[sr][sh * 16 + 8]) = av1;
        if (TN == 128 || tid < 128) {
            const uint4 bv0 = *reinterpret_cast<const uint4*>(bp + k0);
            const uint4 bv1 = *reinterpret_cast<const uint4*>(bp + k0 + 8);
            *reinterpret_cast<uint4*>(&Bs[TN == 128 ? sr : (sr & 63)][sh * 16]) =
                bv0;
            *reinterpret_cast<uint4*>(
                &Bs[TN == 128 ? sr : (sr & 63)][sh * 16 + 8]) = bv1;
        }
        __syncthreads();
        bf16x8 af[MT], bfv[4];
#pragma unroll
        for (int mt = 0; mt < MT; ++mt)
            af[mt] =
                *reinterpret_cast<const bf16x8*>(&As[wm * RB + mt * 16 + fr][kg]);
#pragma unroll
        for (int nt = 0; nt < 4; ++nt)
            bfv[nt] =
                *reinterpret_cast<const bf16x8*>(&Bs[wn * 64 + nt * 16 + fr][kg]);
#pragma unroll
        for (int mt = 0; mt < MT; ++mt)
#pragma unroll
            for (int nt = 0; nt < 4; ++nt)
                acc[mt][nt] = __builtin_amdgcn_mfma_f32_16x16x32_bf16(
                    af[mt], bfv[nt], acc[mt][nt], 0, 0, 0);
        __syncthreads();
    }
    const int rg = (l >> 4) * 4;
#pragma unroll
    for (int nt = 0; nt < 4; ++nt) {
        const int col = col0 + wn * 64 + nt * 16 + fr;
        const float bb = bias[col];
        const float gs = BN_ ? gamma[col] * RS : 0.0f;
        const float bt = BN_ ? beta[col] : 0.0f;
#pragma unroll
        for (int mt = 0; mt < MT; ++mt) {
#pragma unroll
            for (int r = 0; r < 4; ++r) {
                const long row = row0 + wm * RB + mt * 16 + rg + r;
                float v = acc[mt][nt][r] + bb;
                if (ACT) v = eluf(v);
                if (BN_) v = v * gs + bt;
                if (OUTB)
                    reinterpret_cast<__hip_bfloat16*>(outp)[row * Ncols + col] =
                        __float2bfloat16(v);
                else
                    reinterpret_cast<float*>(outp)[row * Ncols + col] = v;
            }
        }
    }
}

// ---------------------------------------------------------------------------
// xchain: fused Xc -> X1 -> X2 with LDS-persistent 128x256 activation panel.
// 256 blocks x 1024 threads = 16 waves (4x4): wave (wm,wn) owns a 32x64
// quadrant. Panel Ap[128][264] bf16 (67.6 KB); per-K-chunk weight tile
// Bs[256][40] (20 KB). Layer: K-loop {stage Bs, barrier, frag-reads + 8 MFMA,
// barrier}; trailing barrier doubles as the all-reads-done fence; epilogue
// (bias/elu) writes bf16 back into Ap (ds_write_b16); X2 writes to global.
// Intermediate roundings identical to the separate-GEMM pipeline.
// ---------------------------------------------------------------------------
__global__ __launch_bounds__(1024) void xchain_kernel(
    const __hip_bfloat16* __restrict__ PLB,  // [32768][64]
    const __hip_bfloat16* __restrict__ cWt,  // [256][64]
    const float* __restrict__ cb,
    const __hip_bfloat16* __restrict__ d1Wt,  // [256][256]
    const float* __restrict__ d1b,
    const __hip_bfloat16* __restrict__ d2Wt,  // [256][256]
    const float* __restrict__ d2b,
    __hip_bfloat16* __restrict__ X2B)  // [32768][256]
{
    __shared__ __bf16 Ap[128][264];
    __shared__ __bf16 Bs[256][40];
    const int tid = threadIdx.x;
    const int w = tid >> 6, l = tid & 63;
    const int wm = w >> 2, wn = w & 3;  // 4x4 waves: 32-row x 64-col quadrants
    const long row0 = (long)blockIdx.x * 128;
    const int fr = l & 15, kg = (l >> 4) * 8, rg = (l >> 4) * 4;

    // stage PLB panel -> Ap[r][0..63]: 1024 uint4, one per thread
    {
        const int r = tid >> 3, q = tid & 7;
        *reinterpret_cast<uint4*>(&Ap[r][q * 8]) =
            *reinterpret_cast<const uint4*>(PLB + (row0 + r) * 64 + q * 8);
    }
    __syncthreads();

    // one layer: acc = Ap(128xK) @ Wt^T; epilogue writes Ap (or X2B if LAST)
    auto layer = [&](const __hip_bfloat16* __restrict__ Wt,
                     const float* __restrict__ bias, int K, bool act,
                     bool last) {
        f32x4 acc[2][4] = {};
        for (int k0 = 0; k0 < K; k0 += 32) {
            // stage Bs[256][32-chunk]: 1024 uint4, one per thread
            {
                const int col = tid >> 2, q = tid & 3;
                *reinterpret_cast<uint4*>(&Bs[col][q * 8]) =
                    *reinterpret_cast<const uint4*>(Wt + (long)col * K + k0 +
                                                    q * 8);
            }
            __syncthreads();
            bf16x8 af[2], bfv[4];
#pragma unroll
            for (int mt = 0; mt < 2; ++mt)
                af[mt] = *reinterpret_cast<const bf16x8*>(
                    &Ap[wm * 32 + mt * 16 + fr][k0 + kg]);
#pragma unroll
            for (int nt = 0; nt < 4; ++nt)
                bfv[nt] = *reinterpret_cast<const bf16x8*>(
                    &Bs[wn * 64 + nt * 16 + fr][kg]);
#pragma unroll
            for (int mt = 0; mt < 2; ++mt)
#pragma unroll
                for (int nt = 0; nt < 4; ++nt)
                    acc[mt][nt] = __builtin_amdgcn_mfma_f32_16x16x32_bf16(
                        af[mt], bfv[nt], acc[mt][nt], 0, 0, 0);
            __syncthreads();  // Bs reuse fence; also all-Ap-reads-done on last
        }
        // epilogue: write back (Ap writes race-free: reads all completed)
#pragma unroll
        for (int nt = 0; nt < 4; ++nt) {
            const int col = wn * 64 + nt * 16 + fr;
            const float bb = bias[col];
#pragma unroll
            for (int mt = 0; mt < 2; ++mt) {
#pragma unroll
                for (int r = 0; r < 4; ++r) {
                    const int row = wm * 32 + mt * 16 + rg + r;
                    float v = acc[mt][nt][r] + bb;
                    if (act) v = eluf(v);
                    const __bf16 h = (__bf16)v;
                    if (last)
                        reinterpret_cast<__hip_bfloat16*>(
                            X2B)[(row0 + row) * 256 + col] =
                            *reinterpret_cast<const __hip_bfloat16*>(&h);
                    else
                        Ap[row][col] = h;
                }
            }
        }
        __syncthreads();  // epilogue writes visible before next layer reads
    };

    layer(cWt, cb, 64, true, false);    // Xc  = elu(PL @ cW + cb)
    layer(d1Wt, d1b, 256, true, false); // X1  = elu(Xc @ d1W + b)
    layer(d2Wt, d2b, 256, false, true); // X2  = X1 @ d2W + b -> global
}

// ---------------------------------------------------------------------------
// Final per-point stage (R12/R9 winner, byte-identical): 1 pt/wave, s_load
// idx, bf16 gather; 1024-thread blocks (16 waves), grid 2048, XCD swizzle.
// No barriers (all LDS wave-private). NOTE: no 2nd __launch_bounds__ arg
// (R4: clamp -> spill).
// ---------------------------------------------------------------------------
__global__ __launch_bounds__(1024) void final_stage_kernel(
    const __hip_bfloat16* __restrict__ X2B,  // [32768][256] bf16
    const float* __restrict__ pts_local,     // [32768][48] (k*3+d)
    const int* __restrict__ pts_idx,
    const __hip_bfloat16* __restrict__ fts_lB,  // [131072][64] bf16
    const float* __restrict__ d1_W, const float* __restrict__ d1_b,
    const float* __restrict__ d1_g, const float* __restrict__ d1_bt,
    const __hip_bfloat16* __restrict__ d2pWt,  // [32 c][32 q] bf16
    const float* __restrict__ d2_b, const float* __restrict__ d2_g,
    const float* __restrict__ d2_bt, const float* __restrict__ dw_W,
    const float* __restrict__ dw_b,
    __hip_bfloat16* __restrict__ dw_out)  // [32768][192] bf16
{
    __shared__ __bf16 fcat[16][96][24];  // wave-private

    const int tid = threadIdx.x;
    const int w = tid >> 6, l = tid & 63;
    const int obid = blockIdx.x;
    const int bid = (obid & 7) * 256 + (obid >> 3);  // bijective, 2048%8==0
    const int gp = bid * 16 + w;
    const int ugp = __builtin_amdgcn_readfirstlane(gp);  // wave-uniform
    const int n = ugp >> 11;
    const int fr = l & 15;
    const int kg = (l >> 4) * 8;
    const int kk = kg & 15;
    const unsigned msk = (l < 32) ? 0xFFFFFFFFu : 0u;
    const int rg4 = (l >> 4) * 4;
    const int colg = (l < 32) ? (32 + l) : (l - 32);
    const __hip_bfloat16* __restrict__ fbase =
        fts_lB + (long)n * 8192 * 64 + colg;

    const int* __restrict__ ip = pts_idx + (long)ugp * 32;
    unsigned fg[16];
#pragma unroll
    for (int j = 0; j < 16; ++j)
        fg[j] = *reinterpret_cast<const unsigned short*>(
            &fbase[(long)ip[2 * j] * 64]);

    const float* __restrict__ pp = pts_local + (long)ugp * 48 + fr * 3;
    const float plA0 = pp[0], plA1 = pp[1], plA2 = pp[2];

    bf16x8 a_l0;
    {
#pragma unroll
        for (int jj = 0; jj < 8; ++jj) {
            const int q = kg + jj;
            float a = d1_b[q];
            a = fmaf(plA0, d1_W[q], a);
            a = fmaf(plA1, d1_W[32 + q], a);
            a = fmaf(plA2, d1_W[64 + q], a);
            a = eluf(a);
            a = a * (d1_g[q] * RS) + d1_bt[q];
            a_l0[jj] = (__bf16)a;
        }
    }

    {
        const bf16x8 b0 =
            *reinterpret_cast<const bf16x8*>(d2pWt + (0 + fr) * 32 + kg);
        const bf16x8 b1 =
            *reinterpret_cast<const bf16x8*>(d2pWt + (16 + fr) * 32 + kg);
        f32x4 lif0 = {}, lif1 = {};
        lif0 = __builtin_amdgcn_mfma_f32_16x16x32_bf16(a_l0, b0, lif0, 0, 0, 0);
        lif1 = __builtin_amdgcn_mfma_f32_16x16x32_bf16(a_l0, b1, lif1, 0, 0, 0);
#pragma unroll
        for (int f = 0; f < 2; ++f) {
            const int c = f * 16 + fr;
            const float bb = d2_b[c], gs = d2_g[c] * RS, bt = d2_bt[c];
            const f32x4 dd = f ? lif1 : lif0;
            unsigned short pk[4];
#pragma unroll
            for (int r = 0; r < 4; ++r) {
                float v = dd[r] + bb;
                v = eluf(v) * gs + bt;
                const __bf16 h = (__bf16)v;
                pk[r] = *reinterpret_cast<const unsigned short*>(&h);
            }
            *reinterpret_cast<uint2*>(&fcat[w][c][rg4]) =
                make_uint2((unsigned)pk[0] | ((unsigned)pk[1] << 16),
                           (unsigned)pk[2] | ((unsigned)pk[3] << 16));
        }
    }

    {
        const uint4 lo = make_uint4(fg[0] | (fg[1] << 16), fg[2] | (fg[3] << 16),
                                    fg[4] | (fg[5] << 16), fg[6] | (fg[7] << 16));
        const uint4 hi =
            make_uint4(fg[8] | (fg[9] << 16), fg[10] | (fg[11] << 16),
                       fg[12] | (fg[13] << 16), fg[14] | (fg[15] << 16));
        *reinterpret_cast<uint4*>(&fcat[w][32 + colg][0]) = lo;
        *reinterpret_cast<uint4*>(&fcat[w][32 + colg][8]) = hi;
    }

    u32x4 axu =
        *reinterpret_cast<const u32x4*>(X2B + (long)ugp * 256 + fr * 16 + kk);
    axu &= msk;
    const bf16x8 ax = *reinterpret_cast<const bf16x8*>(&axu);

    f32x4 acc[6];
#pragma unroll
    for (int f = 0; f < 6; ++f) acc[f] = (f32x4){};
#pragma unroll
    for (int f = 0; f < 6; ++f) {
        u32x4 bu = *reinterpret_cast<const u32x4*>(&fcat[w][f * 16 + fr][kk]);
        bu &= msk;  // zero k>=16 (also kills uninit-LDS NaN)
        const bf16x8 bf = *reinterpret_cast<const bf16x8*>(&bu);
        acc[f] = __builtin_amdgcn_mfma_f32_16x16x32_bf16(ax, bf, acc[f], 0, 0, 0);
    }

    float dwv[6][2];
#pragma unroll
    for (int f = 0; f < 6; ++f) {
        const int c = f * 16 + fr;
        const float4 w0 = *reinterpret_cast<const float4*>(dw_W + c * 32 + rg4);
        const float4 w1 =
            *reinterpret_cast<const float4*>(dw_W + c * 32 + 16 + rg4);
        float p0 = acc[f][0] * w0.x;
        p0 = fmaf(acc[f][1], w0.y, p0);
        p0 = fmaf(acc[f][2], w0.z, p0);
        p0 = fmaf(acc[f][3], w0.w, p0);
        float p1 = acc[f][0] * w1.x;
        p1 = fmaf(acc[f][1], w1.y, p1);
        p1 = fmaf(acc[f][2], w1.z, p1);
        p1 = fmaf(acc[f][3], w1.w, p1);
        p0 += __shfl_xor(p0, 16);
        p0 += __shfl_xor(p0, 32);
        p1 += __shfl_xor(p1, 16);
        p1 += __shfl_xor(p1, 32);
        dwv[f][0] = p0;
        dwv[f][1] = p1;
    }
    if (l < 16) {
#pragma unroll
        for (int f = 0; f < 6; ++f) {
            const int c = f * 16 + l;
            __hip_bfloat162 pk;
            pk.x = __float2bfloat16(dwv[f][0] + dw_b[2 * c + 0]);
            pk.y = __float2bfloat16(dwv[f][1] + dw_b[2 * c + 1]);
            *reinterpret_cast<__hip_bfloat162*>(dw_out + (long)gp * 192 +
                                                2 * c) = pk;
        }
    }
}

extern "C" void kernel_launch(void* const* d_in, const int* in_sizes, int n_in,
                              void* d_out, int out_size, void* d_ws,
                              size_t ws_size, hipStream_t stream) {
    const float* rep_pts = (const float*)d_in[0];
    const float* pts = (const float*)d_in[1];
    const float* fts = (const float*)d_in[2];
    const int* pts_idx = (const int*)d_in[3];
    const float* dense_W = (const float*)d_in[4];
    const float* dense_b = (const float*)d_in[5];
    const float* dense_g = (const float*)d_in[6];
    const float* dense_bt = (const float*)d_in[7];
    const float* d1_W = (const float*)d_in[8];
    const float* d1_b = (const float*)d_in[9];
    const float* d1_g = (const float*)d_in[10];
    const float* d1_bt = (const float*)d_in[11];
    const float* d2_W = (const float*)d_in[12];
    const float* d2_b = (const float*)d_in[13];
    const float* d2_g = (const float*)d_in[14];
    const float* d2_bt = (const float*)d_in[15];
    const float* xt_cW = (const float*)d_in[16];
    const float* xt_cb = (const float*)d_in[17];
    const float* xt_d1W = (const float*)d_in[18];
    const float* xt_d1b = (const float*)d_in[19];
    const float* xt_d2W = (const float*)d_in[20];
    const float* xt_d2b = (const float*)d_in[21];
    const float* dw_W = (const float*)d_in[22];
    const float* dw_b = (const float*)d_in[23];
    const float* pw_W = (const float*)d_in[24];
    const float* pw_b = (const float*)d_in[25];
    const float* sep_g = (const float*)d_in[26];
    const float* sep_bt = (const float*)d_in[27];

    float* ws = (float*)d_ws;
    // Overlay plan (stream-ordered lifetimes):
    //   fts_lB  @ ws+0         : bf16 8388608
    //   X2Bb    @ ws+8388608   : bf16 8388608
    //   region C@ ws+16777216  : ftsB (gather->fts_l) then dwB (final->pw)
    //   region D@ ws+20971520  : PLB (gather->xchain)
    //   pl      @ ws+25165824  : f32 1572864
    //   weights @ ws+26738688..
    __hip_bfloat16* fts_lB = (__hip_bfloat16*)ws;
    __hip_bfloat16* X2Bb = (__hip_bfloat16*)(ws + 8388608);
    __hip_bfloat16* ftsB = (__hip_bfloat16*)(ws + 16777216);
    __hip_bfloat16* dwB = (__hip_bfloat16*)(ws + 16777216);
    __hip_bfloat16* PLB = (__hip_bfloat16*)(ws + 20971520);
    float* pl = ws + 25165824;
    __hip_bfloat16* d1Wt = (__hip_bfloat16*)(ws + 26738688);     // 65536
    __hip_bfloat16* d2Wt = (__hip_bfloat16*)(ws + 26771456);     // 65536
    __hip_bfloat16* pwWt = (__hip_bfloat16*)(ws + 26804224);     // 24576
    __hip_bfloat16* d2pWt = (__hip_bfloat16*)(ws + 26816512);    // 1024
    __hip_bfloat16* denseWt = (__hip_bfloat16*)(ws + 26817024);  // 4096
    __hip_bfloat16* cWt = (__hip_bfloat16*)(ws + 26819072);      // 16384

    // 0) weight convert+transpose to bf16
    convert_weights<<<256, 256, 0, stream>>>(xt_d1W, xt_d2W, pw_W, d2_W,
                                             dense_W, xt_cW, d1Wt, d2Wt, pwWt,
                                             d2pWt, denseWt, cWt);

    // 1) gather: pts_local + PLB + fts cast
    gather_kernel<<<2048, 256, 0, stream>>>(rep_pts, pts, pts_idx, fts, pl, PLB,
                                            ftsB);

    // 2) fts_l = bn(elu(fts @ dense_W + b))  MFMA TN=64, K=64
    mfma_gemm<64, 1, 1, 1><<<dim3(1024, 1), 256, 0, stream>>>(
        ftsB, denseWt, dense_b, dense_g, dense_bt, fts_lB, 64, 64);

    // 3) xchain: Xc -> X1 -> X2 fused (panel-persistent LDS)
    xchain_kernel<<<256, 1024, 0, stream>>>(PLB, cWt, xt_cb, d1Wt, xt_d1b,
                                            d2Wt, xt_d2b, X2Bb);

    // 4) lifted/gather/fts_X/dw -> dwB
    final_stage_kernel<<<2048, 1024, 0, stream>>>(
        X2Bb, pl, pts_idx, fts_lB, d1_W, d1_b, d1_g, d1_bt, d2pWt, d2_b, d2_g,
        d2_bt, dw_W, dw_b, dwB);

    // 5) out = bn(elu(dw @ pw_W + pw_b))  MFMA -> f32
    mfma_gemm<128, 1, 1, 0><<<dim3(256, 1), 256, 0, stream>>>(
        dwB, pwWt, pw_b, sep_g, sep_bt, d_out, 192, 128);
}

// Round 15
// 91.402 us; speedup vs baseline: 2.1882x; 1.5094x over previous
//
#include <hip/hip_runtime.h>
#include <hip/hip_bf16.h>

#define RS 0.9999950000374998f  // 1/sqrt(1+1e-5)

__device__ __forceinline__ float eluf(float x) {
    return x > 0.0f ? x : __expf(x) - 1.0f;
}

typedef __attribute__((ext_vector_type(8))) __bf16 bf16x8;
typedef __attribute__((ext_vector_type(4))) float f32x4;
typedef __attribute__((ext_vector_type(4))) unsigned int u32x4;

// ---------------------------------------------------------------------------
// Gather + weight-convert (fused): blocks 0..255 also convert weights to
// bf16-transposed. Per-point part: pts_local f32 [32768][48] (k*3+d) + PLB
// bf16 [32768][64] (d*16+k, cols 48-63 zero). 16 pts/block, grid 2048.
// ---------------------------------------------------------------------------
__global__ __launch_bounds__(256) void gather_kernel(
    const float* __restrict__ rep_pts, const float* __restrict__ pts,
    const int* __restrict__ pts_idx, const float* __restrict__ d1W,
    const float* __restrict__ d2W, const float* __restrict__ pwW,
    const float* __restrict__ d2Ws, const float* __restrict__ denseW,
    const float* __restrict__ cW, float* __restrict__ pts_local,
    __hip_bfloat16* __restrict__ PLB, __hip_bfloat16* __restrict__ d1Wt,
    __hip_bfloat16* __restrict__ d2Wt, __hip_bfloat16* __restrict__ pwWt,
    __hip_bfloat16* __restrict__ d2pWt, __hip_bfloat16* __restrict__ denseWt,
    __hip_bfloat16* __restrict__ cWt) {
    const int tid = threadIdx.x;
    // ---- weight conversion (first 256 blocks = 65536 threads) ----
    if (blockIdx.x < 256) {
        const int t = blockIdx.x * 256 + tid;
        {
            const int k = t >> 8, n = t & 255;
            d1Wt[n * 256 + k] = __float2bfloat16(d1W[t]);
            d2Wt[n * 256 + k] = __float2bfloat16(d2W[t]);
        }
        if (t < 24576) {
            const int k = t >> 7, n = t & 127;
            pwWt[n * 192 + k] = __float2bfloat16(pwW[t]);
        }
        if (t < 1024) {
            const int q = t >> 5, c = t & 31;
            d2pWt[c * 32 + q] = __float2bfloat16(d2Ws[t]);
        }
        if (t < 4096) {
            const int k = t >> 6, n = t & 63;
            denseWt[n * 64 + k] = __float2bfloat16(denseW[t]);
        }
        if (t < 16384) {
            const int o = t >> 6, kq = t & 63;
            cWt[t] = (kq < 48) ? __float2bfloat16(cW[o * 48 + kq])
                               : __float2bfloat16(0.0f);
        }
    }
    // ---- per-point gather ----
    const long gp0 = (long)blockIdx.x * 16;
    const int pt = tid >> 4, k = tid & 15;
    const long gp = gp0 + pt;
    const int n = (int)(gp >> 11);
    const int idx = pts_idx[gp * 32 + 2 * k];
    const float* ps = pts + ((long)n * 8192 + idx) * 3;
    const float* rs = rep_pts + gp * 3;
#pragma unroll
    for (int d = 0; d < 3; ++d) {
        const float v = ps[d] - rs[d];
        pts_local[gp * 48 + k * 3 + d] = v;
        PLB[gp * 64 + d * 16 + k] = __float2bfloat16(v);
    }
    PLB[gp * 64 + 48 + k] = __float2bfloat16(0.0f);
}

// ---------------------------------------------------------------------------
// bf16 MFMA GEMM (pw): out = post(A @ Wt^T + bias), Wt pre-transposed [N][K].
// TN=128 tile 128x128, 4 waves 2x2.
// ---------------------------------------------------------------------------
template <int TN, int ACT, int BN_, int OUTB>
__global__ __launch_bounds__(256) void mfma_gemm(
    const __hip_bfloat16* __restrict__ A, const __hip_bfloat16* __restrict__ Wt,
    const float* __restrict__ bias, const float* __restrict__ gamma,
    const float* __restrict__ beta, void* __restrict__ outp, int K, int Ncols) {
    constexpr int MT = (TN == 128) ? 4 : 2;
    constexpr int RB = MT * 16;
    __shared__ __bf16 As[128][40];
    __shared__ __bf16 Bs[TN][40];
    const int tid = threadIdx.x;
    const int w = tid >> 6, l = tid & 63;
    const int wm = (TN == 128) ? (w >> 1) : w;
    const int wn = (TN == 128) ? (w & 1) : 0;
    const long row0 = (long)blockIdx.x * 128;
    const int col0 = blockIdx.y * TN;
    const int sr = tid >> 1, sh = tid & 1;
    const int fr = l & 15, kg = (l >> 4) * 8;
    f32x4 acc[MT][4] = {};
    const __hip_bfloat16* __restrict__ ap = A + (row0 + sr) * (long)K + sh * 16;
    const __hip_bfloat16* __restrict__ bp =
        Wt + (long)(col0 + (TN == 128 ? sr : (sr & 63))) * K + sh * 16;
    for (int k0 = 0; k0 < K; k0 += 32) {
        const uint4 av0 = *reinterpret_cast<const uint4*>(ap + k0);
        const uint4 av1 = *reinterpret_cast<const uint4*>(ap + k0 + 8);
        *reinterpret_cast<uint4*>(&As[sr][sh * 16]) = av0;
        *reinterpret_cast<uint4*>(&As[sr][sh * 16 + 8]) = av1;
        if (TN == 128 || tid < 128) {
            const uint4 bv0 = *reinterpret_cast<const uint4*>(bp + k0);
            const uint4 bv1 = *reinterpret_cast<const uint4*>(bp + k0 + 8);
            *reinterpret_cast<uint4*>(&Bs[TN == 128 ? sr : (sr & 63)][sh * 16]) =
                bv0;
            *reinterpret_cast<uint4*>(
                &Bs[TN == 128 ? sr : (sr & 63)][sh * 16 + 8]) = bv1;
        }
        __syncthreads();
        bf16x8 af[MT], bfv[4];
#pragma unroll
        for (int mt = 0; mt < MT; ++mt)
            af[mt] =
                *reinterpret_cast<const bf16x8*>(&As[wm * RB + mt * 16 + fr][kg]);
#pragma unroll
        for (int nt = 0; nt < 4; ++nt)
            bfv[nt] =
                *reinterpret_cast<const bf16x8*>(&Bs[wn * 64 + nt * 16 + fr][kg]);
#pragma unroll
        for (int mt = 0; mt < MT; ++mt)
#pragma unroll
            for (int nt = 0; nt < 4; ++nt)
                acc[mt][nt] = __builtin_amdgcn_mfma_f32_16x16x32_bf16(
                    af[mt], bfv[nt], acc[mt][nt], 0, 0, 0);
        __syncthreads();
    }
    const int rg = (l >> 4) * 4;
#pragma unroll
    for (int nt = 0; nt < 4; ++nt) {
        const int col = col0 + wn * 64 + nt * 16 + fr;
        const float bb = bias[col];
        const float gs = BN_ ? gamma[col] * RS : 0.0f;
        const float bt = BN_ ? beta[col] : 0.0f;
#pragma unroll
        for (int mt = 0; mt < MT; ++mt) {
#pragma unroll
            for (int r = 0; r < 4; ++r) {
                const long row = row0 + wm * RB + mt * 16 + rg + r;
                float v = acc[mt][nt][r] + bb;
                if (ACT) v = eluf(v);
                if (BN_) v = v * gs + bt;
                if (OUTB)
                    reinterpret_cast<__hip_bfloat16*>(outp)[row * Ncols + col] =
                        __float2bfloat16(v);
                else
                    reinterpret_cast<float*>(outp)[row * Ncols + col] = v;
            }
        }
    }
}

// ---------------------------------------------------------------------------
// fts_l GEMM with f32 A input (converts to bf16 in staging — bitwise same as
// the old cast+bf16-GEMM path). TN=64: tile 128x64, 4 waves stacked, K=64.
// ---------------------------------------------------------------------------
__global__ __launch_bounds__(256) void mfma_gemm_f32a64(
    const float* __restrict__ A, const __hip_bfloat16* __restrict__ Wt,
    const float* __restrict__ bias, const float* __restrict__ gamma,
    const float* __restrict__ beta, __hip_bfloat16* __restrict__ outp, int K,
    int Ncols) {
    __shared__ __bf16 As[128][40];
    __shared__ __bf16 Bs[64][40];
    const int tid = threadIdx.x;
    const int w = tid >> 6, l = tid & 63;
    const long row0 = (long)blockIdx.x * 128;
    const int sr = tid >> 1, sh = tid & 1;
    const int fr = l & 15, kg = (l >> 4) * 8;
    f32x4 acc[2][4] = {};
    const float* __restrict__ ap = A + (row0 + sr) * (long)K + sh * 16;
    const __hip_bfloat16* __restrict__ bp = Wt + (long)(sr & 63) * K + sh * 16;
    for (int k0 = 0; k0 < K; k0 += 32) {
        float av[16];
#pragma unroll
        for (int q = 0; q < 4; ++q) {
            const float4 v = *reinterpret_cast<const float4*>(ap + k0 + q * 4);
            av[q * 4 + 0] = v.x;
            av[q * 4 + 1] = v.y;
            av[q * 4 + 2] = v.z;
            av[q * 4 + 3] = v.w;
        }
        union {
            __bf16 b[16];
            uint4 u[2];
        } cv;
#pragma unroll
        for (int e = 0; e < 16; ++e) cv.b[e] = (__bf16)av[e];
        *reinterpret_cast<uint4*>(&As[sr][sh * 16]) = cv.u[0];
        *reinterpret_cast<uint4*>(&As[sr][sh * 16 + 8]) = cv.u[1];
        if (tid < 128) {
            const uint4 bv0 = *reinterpret_cast<const uint4*>(bp + k0);
            const uint4 bv1 = *reinterpret_cast<const uint4*>(bp + k0 + 8);
            *reinterpret_cast<uint4*>(&Bs[sr & 63][sh * 16]) = bv0;
            *reinterpret_cast<uint4*>(&Bs[sr & 63][sh * 16 + 8]) = bv1;
        }
        __syncthreads();
        bf16x8 af[2], bfv[4];
#pragma unroll
        for (int mt = 0; mt < 2; ++mt)
            af[mt] =
                *reinterpret_cast<const bf16x8*>(&As[w * 32 + mt * 16 + fr][kg]);
#pragma unroll
        for (int nt = 0; nt < 4; ++nt)
            bfv[nt] = *reinterpret_cast<const bf16x8*>(&Bs[nt * 16 + fr][kg]);
#pragma unroll
        for (int mt = 0; mt < 2; ++mt)
#pragma unroll
            for (int nt = 0; nt < 4; ++nt)
                acc[mt][nt] = __builtin_amdgcn_mfma_f32_16x16x32_bf16(
                    af[mt], bfv[nt], acc[mt][nt], 0, 0, 0);
        __syncthreads();
    }
    const int rg = (l >> 4) * 4;
#pragma unroll
    for (int nt = 0; nt < 4; ++nt) {
        const int col = nt * 16 + fr;
        const float bb = bias[col];
        const float gs = gamma[col] * RS;
        const float bt = beta[col];
#pragma unroll
        for (int mt = 0; mt < 2; ++mt) {
#pragma unroll
            for (int r = 0; r < 4; ++r) {
                const long row = row0 + w * 32 + mt * 16 + rg + r;
                float v = acc[mt][nt][r] + bb;
                v = eluf(v) * gs + bt;
                outp[row * Ncols + col] = __float2bfloat16(v);
            }
        }
    }
}

// ---------------------------------------------------------------------------
// xchain (R14 winner): fused Xc -> X1 -> X2, LDS-persistent 128x256 panel.
// 256 blocks x 1024 threads (4x4 waves, 32x64 quadrants).
// ---------------------------------------------------------------------------
__global__ __launch_bounds__(1024) void xchain_kernel(
    const __hip_bfloat16* __restrict__ PLB, const __hip_bfloat16* __restrict__ cWt,
    const float* __restrict__ cb, const __hip_bfloat16* __restrict__ d1Wt,
    const float* __restrict__ d1b, const __hip_bfloat16* __restrict__ d2Wt,
    const float* __restrict__ d2b, __hip_bfloat16* __restrict__ X2B) {
    __shared__ __bf16 Ap[128][264];
    __shared__ __bf16 Bs[256][40];
    const int tid = threadIdx.x;
    const int w = tid >> 6, l = tid & 63;
    const int wm = w >> 2, wn = w & 3;
    const long row0 = (long)blockIdx.x * 128;
    const int fr = l & 15, kg = (l >> 4) * 8, rg = (l >> 4) * 4;

    {
        const int r = tid >> 3, q = tid & 7;
        *reinterpret_cast<uint4*>(&Ap[r][q * 8]) =
            *reinterpret_cast<const uint4*>(PLB + (row0 + r) * 64 + q * 8);
    }
    __syncthreads();

    auto layer = [&](const __hip_bfloat16* __restrict__ Wt,
                     const float* __restrict__ bias, int K, bool act,
                     bool last) {
        f32x4 acc[2][4] = {};
        for (int k0 = 0; k0 < K; k0 += 32) {
            {
                const int col = tid >> 2, q = tid & 3;
                *reinterpret_cast<uint4*>(&Bs[col][q * 8]) =
                    *reinterpret_cast<const uint4*>(Wt + (long)col * K + k0 +
                                                    q * 8);
            }
            __syncthreads();
            bf16x8 af[2], bfv[4];
#pragma unroll
            for (int mt = 0; mt < 2; ++mt)
                af[mt] = *reinterpret_cast<const bf16x8*>(
                    &Ap[wm * 32 + mt * 16 + fr][k0 + kg]);
#pragma unroll
            for (int nt = 0; nt < 4; ++nt)
                bfv[nt] = *reinterpret_cast<const bf16x8*>(
                    &Bs[wn * 64 + nt * 16 + fr][kg]);
#pragma unroll
            for (int mt = 0; mt < 2; ++mt)
#pragma unroll
                for (int nt = 0; nt < 4; ++nt)
                    acc[mt][nt] = __builtin_amdgcn_mfma_f32_16x16x32_bf16(
                        af[mt], bfv[nt], acc[mt][nt], 0, 0, 0);
            __syncthreads();
        }
#pragma unroll
        for (int nt = 0; nt < 4; ++nt) {
            const int col = wn * 64 + nt * 16 + fr;
            const float bb = bias[col];
#pragma unroll
            for (int mt = 0; mt < 2; ++mt) {
#pragma unroll
                for (int r = 0; r < 4; ++r) {
                    const int row = wm * 32 + mt * 16 + rg + r;
                    float v = acc[mt][nt][r] + bb;
                    if (act) v = eluf(v);
                    const __bf16 h = (__bf16)v;
                    if (last)
                        X2B[(row0 + row) * 256 + col] =
                            *reinterpret_cast<const __hip_bfloat16*>(&h);
                    else
                        Ap[row][col] = h;
                }
            }
        }
        __syncthreads();
    };

    layer(cWt, cb, 64, true, false);
    layer(d1Wt, d1b, 256, true, false);
    layer(d2Wt, d2b, 256, false, true);
}

// ---------------------------------------------------------------------------
// Final per-point stage v11: R12 body + block-level LDS weight staging.
// Per-wave vmem ops drop ~106 -> ~22 (weights read once per block, not per
// wave). fcat rows shrunk 24->16 elems (all reads/writes <=16; 32B rows keep
// 16B alignment; 4-way banks on ~15 LDS ops = negligible). LDS 64.9 KB ->
// still 2 blocks/CU. One staging barrier; rest barrier-free.
// Arithmetic identical to v10 (staging is f32). NOTE: no 2nd launch_bounds
// arg (R4: clamp -> spill).
// ---------------------------------------------------------------------------
__global__ __launch_bounds__(1024) void final_stage_kernel(
    const __hip_bfloat16* __restrict__ X2B,  // [32768][256] bf16
    const float* __restrict__ pts_local,     // [32768][48] (k*3+d)
    const int* __restrict__ pts_idx,
    const __hip_bfloat16* __restrict__ fts_lB,  // [131072][64] bf16
    const float* __restrict__ d1_W, const float* __restrict__ d1_b,
    const float* __restrict__ d1_g, const float* __restrict__ d1_bt,
    const __hip_bfloat16* __restrict__ d2pWt,  // [32 c][32 q] bf16
    const float* __restrict__ d2_b, const float* __restrict__ d2_g,
    const float* __restrict__ d2_bt, const float* __restrict__ dw_W,
    const float* __restrict__ dw_b,
    __hip_bfloat16* __restrict__ dw_out)  // [32768][192] bf16
{
    __shared__ __bf16 fcat[16][96][16];  // 49152 B, wave-private
    __shared__ float dwT[96][36];        // 13824 B (row 144B, 16B-aligned)
    __shared__ float wd1[6][32];         // d1_W rows 0-2; b; g*RS; bt
    __shared__ float d2e[3][32];         // d2_b; d2_g*RS; d2_bt
    __shared__ float dwbs[192];          // dw_b

    const int tid = threadIdx.x;
    const int w = tid >> 6, l = tid & 63;

    // ---- block-level weight staging (one barrier) ----
    for (int i = tid; i < 3072; i += 1024) dwT[i >> 5][i & 31] = dw_W[i];
    if (tid < 96) wd1[tid >> 5][tid & 31] = d1_W[tid];
    else if (tid < 128) wd1[3][tid & 31] = d1_b[tid & 31];
    else if (tid < 160) wd1[4][tid & 31] = d1_g[tid & 31] * RS;
    else if (tid < 192) wd1[5][tid & 31] = d1_bt[tid & 31];
    else if (tid < 224) d2e[0][tid & 31] = d2_b[tid & 31];
    else if (tid < 256) d2e[1][tid & 31] = d2_g[tid & 31] * RS;
    else if (tid < 288) d2e[2][tid & 31] = d2_bt[tid & 31];
    else if (tid < 480) dwbs[tid - 288] = dw_b[tid - 288];
    __syncthreads();

    const int obid = blockIdx.x;
    const int bid = (obid & 7) * 256 + (obid >> 3);  // bijective, 2048%8==0
    const int gp = bid * 16 + w;
    const int ugp = __builtin_amdgcn_readfirstlane(gp);  // wave-uniform
    const int n = ugp >> 11;
    const int fr = l & 15;
    const int kg = (l >> 4) * 8;
    const int kk = kg & 15;
    const unsigned msk = (l < 32) ? 0xFFFFFFFFu : 0u;
    const int rg4 = (l >> 4) * 4;
    const int colg = (l < 32) ? (32 + l) : (l - 32);
    const __hip_bfloat16* __restrict__ fbase =
        fts_lB + (long)n * 8192 * 64 + colg;

    // ---- fts gather: lane owns bf16 col colg, 16 rows (idx via s_load) ----
    const int* __restrict__ ip = pts_idx + (long)ugp * 32;
    unsigned fg[16];
#pragma unroll
    for (int j = 0; j < 16; ++j)
        fg[j] = *reinterpret_cast<const unsigned short*>(
            &fbase[(long)ip[2 * j] * 64]);

    const float* __restrict__ pp = pts_local + (long)ugp * 48 + fr * 3;
    const float plA0 = pp[0], plA1 = pp[1], plA2 = pp[2];

    // ---- l0 row-owner A-frag: lane = row fr, k-cols kg..kg+7 ----
    bf16x8 a_l0;
#pragma unroll
    for (int jj = 0; jj < 8; ++jj) {
        const int q = kg + jj;  // uniform within 16-lane group -> broadcast
        float a = wd1[3][q];
        a = fmaf(plA0, wd1[0][q], a);
        a = fmaf(plA1, wd1[1][q], a);
        a = fmaf(plA2, wd1[2][q], a);
        a = eluf(a);
        a = a * wd1[4][q] + wd1[5][q];
        a_l0[jj] = (__bf16)a;
    }

    // ---- lifted = l0 @ d2_W via 2 MFMA -> fcat cols 0..31 ----
    {
        const bf16x8 b0 =
            *reinterpret_cast<const bf16x8*>(d2pWt + (0 + fr) * 32 + kg);
        const bf16x8 b1 =
            *reinterpret_cast<const bf16x8*>(d2pWt + (16 + fr) * 32 + kg);
        f32x4 lif0 = {}, lif1 = {};
        lif0 = __builtin_amdgcn_mfma_f32_16x16x32_bf16(a_l0, b0, lif0, 0, 0, 0);
        lif1 = __builtin_amdgcn_mfma_f32_16x16x32_bf16(a_l0, b1, lif1, 0, 0, 0);
#pragma unroll
        for (int f = 0; f < 2; ++f) {
            const int c = f * 16 + fr;
            const float bb = d2e[0][c & 31], gs = d2e[1][c & 31],
                        bt = d2e[2][c & 31];
            const f32x4 dd = f ? lif1 : lif0;
            unsigned short pk[4];
#pragma unroll
            for (int r = 0; r < 4; ++r) {
                float v = dd[r] + bb;
                v = eluf(v) * gs + bt;
                const __bf16 h = (__bf16)v;
                pk[r] = *reinterpret_cast<const unsigned short*>(&h);
            }
            *reinterpret_cast<uint2*>(&fcat[w][c][rg4]) =
                make_uint2((unsigned)pk[0] | ((unsigned)pk[1] << 16),
                           (unsigned)pk[2] | ((unsigned)pk[3] << 16));
        }
    }

    // ---- fg (bf16 bits) -> fcat[32+colg][0..15] (2 x ds_write_b128) ----
    {
        const uint4 lo = make_uint4(fg[0] | (fg[1] << 16), fg[2] | (fg[3] << 16),
                                    fg[4] | (fg[5] << 16), fg[6] | (fg[7] << 16));
        const uint4 hi =
            make_uint4(fg[8] | (fg[9] << 16), fg[10] | (fg[11] << 16),
                       fg[12] | (fg[13] << 16), fg[14] | (fg[15] << 16));
        *reinterpret_cast<uint4*>(&fcat[w][32 + colg][0]) = lo;
        *reinterpret_cast<uint4*>(&fcat[w][32 + colg][8]) = hi;
    }

    // ---- A-frag: X row fr (zero k>=16 half via mask) ----
    u32x4 axu =
        *reinterpret_cast<const u32x4*>(X2B + (long)ugp * 256 + fr * 16 + kk);
    axu &= msk;
    const bf16x8 ax = *reinterpret_cast<const bf16x8*>(&axu);

    // ---- fts_X: 6 B-frags from fcat + 6 MFMA ----
    f32x4 acc[6];
#pragma unroll
    for (int f = 0; f < 6; ++f) acc[f] = (f32x4){};
#pragma unroll
    for (int f = 0; f < 6; ++f) {
        u32x4 bu = *reinterpret_cast<const u32x4*>(&fcat[w][f * 16 + fr][kk]);
        bu &= msk;  // zero k>=16 (also kills uninit-LDS NaN)
        const bf16x8 bf = *reinterpret_cast<const bf16x8*>(&bu);
        acc[f] = __builtin_amdgcn_mfma_f32_16x16x32_bf16(ax, bf, acc[f], 0, 0, 0);
    }

    // ---- dw: partials rows rg4..rg4+3, butterfly, store (lanes<16) ----
    float dwv[6][2];
#pragma unroll
    for (int f = 0; f < 6; ++f) {
        const int c = f * 16 + fr;
        const float4 w0 = *reinterpret_cast<const float4*>(&dwT[c][rg4]);
        const float4 w1 = *reinterpret_cast<const float4*>(&dwT[c][16 + rg4]);
        float p0 = acc[f][0] * w0.x;
        p0 = fmaf(acc[f][1], w0.y, p0);
        p0 = fmaf(acc[f][2], w0.z, p0);
        p0 = fmaf(acc[f][3], w0.w, p0);
        float p1 = acc[f][0] * w1.x;
        p1 = fmaf(acc[f][1], w1.y, p1);
        p1 = fmaf(acc[f][2], w1.z, p1);
        p1 = fmaf(acc[f][3], w1.w, p1);
        p0 += __shfl_xor(p0, 16);
        p0 += __shfl_xor(p0, 32);
        p1 += __shfl_xor(p1, 16);
        p1 += __shfl_xor(p1, 32);
        dwv[f][0] = p0;
        dwv[f][1] = p1;
    }
    if (l < 16) {
#pragma unroll
        for (int f = 0; f < 6; ++f) {
            const int c = f * 16 + l;
            __hip_bfloat162 pk;
            pk.x = __float2bfloat16(dwv[f][0] + dwbs[2 * c + 0]);
            pk.y = __float2bfloat16(dwv[f][1] + dwbs[2 * c + 1]);
            *reinterpret_cast<__hip_bfloat162*>(dw_out + (long)gp * 192 +
                                                2 * c) = pk;
        }
    }
}

extern "C" void kernel_launch(void* const* d_in, const int* in_sizes, int n_in,
                              void* d_out, int out_size, void* d_ws,
                              size_t ws_size, hipStream_t stream) {
    const float* rep_pts = (const float*)d_in[0];
    const float* pts = (const float*)d_in[1];
    const float* fts = (const float*)d_in[2];
    const int* pts_idx = (const int*)d_in[3];
    const float* dense_W = (const float*)d_in[4];
    const float* dense_b = (const float*)d_in[5];
    const float* dense_g = (const float*)d_in[6];
    const float* dense_bt = (const float*)d_in[7];
    const float* d1_W = (const float*)d_in[8];
    const float* d1_b = (const float*)d_in[9];
    const float* d1_g = (const float*)d_in[10];
    const float* d1_bt = (const float*)d_in[11];
    const float* d2_W = (const float*)d_in[12];
    const float* d2_b = (const float*)d_in[13];
    const float* d2_g = (const float*)d_in[14];
    const float* d2_bt = (const float*)d_in[15];
    const float* xt_cW = (const float*)d_in[16];
    const float* xt_cb = (const float*)d_in[17];
    const float* xt_d1W = (const float*)d_in[18];
    const float* xt_d1b = (const float*)d_in[19];
    const float* xt_d2W = (const float*)d_in[20];
    const float* xt_d2b = (const float*)d_in[21];
    const float* dw_W = (const float*)d_in[22];
    const float* dw_b = (const float*)d_in[23];
    const float* pw_W = (const float*)d_in[24];
    const float* pw_b = (const float*)d_in[25];
    const float* sep_g = (const float*)d_in[26];
    const float* sep_bt = (const float*)d_in[27];

    float* ws = (float*)d_ws;
    // Overlay plan (stream-ordered lifetimes):
    //   fts_lB  @ ws+0         : bf16 8388608
    //   X2Bb    @ ws+8388608   : bf16 8388608
    //   region C@ ws+16777216  : dwB (final->pw)
    //   region D@ ws+20971520  : PLB (gather->xchain)
    //   pl      @ ws+25165824  : f32 1572864
    //   weights @ ws+26738688..
    __hip_bfloat16* fts_lB = (__hip_bfloat16*)ws;
    __hip_bfloat16* X2Bb = (__hip_bfloat16*)(ws + 8388608);
    __hip_bfloat16* dwB = (__hip_bfloat16*)(ws + 16777216);
    __hip_bfloat16* PLB = (__hip_bfloat16*)(ws + 20971520);
    float* pl = ws + 25165824;
    __hip_bfloat16* d1Wt = (__hip_bfloat16*)(ws + 26738688);     // 65536
    __hip_bfloat16* d2Wt = (__hip_bfloat16*)(ws + 26771456);     // 65536
    __hip_bfloat16* pwWt = (__hip_bfloat16*)(ws + 26804224);     // 24576
    __hip_bfloat16* d2pWt = (__hip_bfloat16*)(ws + 26816512);    // 1024
    __hip_bfloat16* denseWt = (__hip_bfloat16*)(ws + 26817024);  // 4096
    __hip_bfloat16* cWt = (__hip_bfloat16*)(ws + 26819072);      // 16384

    // 1) gather (+ fused weight convert): pts_local + PLB
    gather_kernel<<<2048, 256, 0, stream>>>(
        rep_pts, pts, pts_idx, xt_d1W, xt_d2W, pw_W, d2_W, dense_W, xt_cW, pl,
        PLB, d1Wt, d2Wt, pwWt, d2pWt, denseWt, cWt);

    // 2) fts_l = bn(elu(fts @ dense_W + b))  f32-A MFMA TN=64, K=64
    mfma_gemm_f32a64<<<dim3(1024, 1), 256, 0, stream>>>(
        fts, denseWt, dense_b, dense_g, dense_bt, fts_lB, 64, 64);

    // 3) xchain: Xc -> X1 -> X2 fused (panel-persistent LDS)
    xchain_kernel<<<256, 1024, 0, stream>>>(PLB, cWt, xt_cb, d1Wt, xt_d1b,
                                            d2Wt, xt_d2b, X2Bb);

    // 4) lifted/gather/fts_X/dw -> dwB (LDS weight staging)
    final_stage_kernel<<<2048, 1024, 0, stream>>>(
        X2Bb, pl, pts_idx, fts_lB, d1_W, d1_b, d1_g, d1_bt, d2pWt, d2_b, d2_g,
        d2_bt, dw_W, dw_b, dwB);

    // 5) out = bn(elu(dw @ pw_W + pw_b))  MFMA -> f32
    mfma_gemm<128, 1, 1, 0><<<dim3(256, 1), 256, 0, stream>>>(
        dwB, pwWt, pw_b, sep_g, sep_bt, d_out, 192, 128);
}

// Round 16
// 90.087 us; speedup vs baseline: 2.2201x; 1.0146x over previous
//
#include <hip/hip_runtime.h>
#include <hip/hip_bf16.h>

#define RS 0.9999950000374998f  // 1/sqrt(1+1e-5)

__device__ __forceinline__ float eluf(float x) {
    return x > 0.0f ? x : __expf(x) - 1.0f;
}

typedef __attribute__((ext_vector_type(8))) __bf16 bf16x8;
typedef __attribute__((ext_vector_type(4))) float f32x4;
typedef __attribute__((ext_vector_type(4))) unsigned int u32x4;

// ---------------------------------------------------------------------------
// Gather + weight-convert (fused): blocks 0..255 also convert weights to
// bf16-transposed. Per-point part: pts_local f32 [32768][48] (k*3+d) + PLB
// bf16 [32768][64] (d*16+k, cols 48-63 zero). 16 pts/block, grid 2048.
// ---------------------------------------------------------------------------
__global__ __launch_bounds__(256) void gather_kernel(
    const float* __restrict__ rep_pts, const float* __restrict__ pts,
    const int* __restrict__ pts_idx, const float* __restrict__ d1W,
    const float* __restrict__ d2W, const float* __restrict__ pwW,
    const float* __restrict__ d2Ws, const float* __restrict__ denseW,
    const float* __restrict__ cW, float* __restrict__ pts_local,
    __hip_bfloat16* __restrict__ PLB, __hip_bfloat16* __restrict__ d1Wt,
    __hip_bfloat16* __restrict__ d2Wt, __hip_bfloat16* __restrict__ pwWt,
    __hip_bfloat16* __restrict__ d2pWt, __hip_bfloat16* __restrict__ denseWt,
    __hip_bfloat16* __restrict__ cWt) {
    const int tid = threadIdx.x;
    if (blockIdx.x < 256) {
        const int t = blockIdx.x * 256 + tid;
        {
            const int k = t >> 8, n = t & 255;
            d1Wt[n * 256 + k] = __float2bfloat16(d1W[t]);
            d2Wt[n * 256 + k] = __float2bfloat16(d2W[t]);
        }
        if (t < 24576) {
            const int k = t >> 7, n = t & 127;
            pwWt[n * 192 + k] = __float2bfloat16(pwW[t]);
        }
        if (t < 1024) {
            const int q = t >> 5, c = t & 31;
            d2pWt[c * 32 + q] = __float2bfloat16(d2Ws[t]);
        }
        if (t < 4096) {
            const int k = t >> 6, n = t & 63;
            denseWt[n * 64 + k] = __float2bfloat16(denseW[t]);
        }
        if (t < 16384) {
            const int o = t >> 6, kq = t & 63;
            cWt[t] = (kq < 48) ? __float2bfloat16(cW[o * 48 + kq])
                               : __float2bfloat16(0.0f);
        }
    }
    const long gp0 = (long)blockIdx.x * 16;
    const int pt = tid >> 4, k = tid & 15;
    const long gp = gp0 + pt;
    const int n = (int)(gp >> 11);
    const int idx = pts_idx[gp * 32 + 2 * k];
    const float* ps = pts + ((long)n * 8192 + idx) * 3;
    const float* rs = rep_pts + gp * 3;
#pragma unroll
    for (int d = 0; d < 3; ++d) {
        const float v = ps[d] - rs[d];
        pts_local[gp * 48 + k * 3 + d] = v;
        PLB[gp * 64 + d * 16 + k] = __float2bfloat16(v);
    }
    PLB[gp * 64 + 48 + k] = __float2bfloat16(0.0f);
}

// ---------------------------------------------------------------------------
// fts_l GEMM with f32 A input (converts to bf16 in staging). TN=64:
// tile 128x64, 4 waves stacked, K=64.
// ---------------------------------------------------------------------------
__global__ __launch_bounds__(256) void mfma_gemm_f32a64(
    const float* __restrict__ A, const __hip_bfloat16* __restrict__ Wt,
    const float* __restrict__ bias, const float* __restrict__ gamma,
    const float* __restrict__ beta, __hip_bfloat16* __restrict__ outp, int K,
    int Ncols) {
    __shared__ __bf16 As[128][40];
    __shared__ __bf16 Bs[64][40];
    const int tid = threadIdx.x;
    const int w = tid >> 6, l = tid & 63;
    const long row0 = (long)blockIdx.x * 128;
    const int sr = tid >> 1, sh = tid & 1;
    const int fr = l & 15, kg = (l >> 4) * 8;
    f32x4 acc[2][4] = {};
    const float* __restrict__ ap = A + (row0 + sr) * (long)K + sh * 16;
    const __hip_bfloat16* __restrict__ bp = Wt + (long)(sr & 63) * K + sh * 16;
    for (int k0 = 0; k0 < K; k0 += 32) {
        float av[16];
#pragma unroll
        for (int q = 0; q < 4; ++q) {
            const float4 v = *reinterpret_cast<const float4*>(ap + k0 + q * 4);
            av[q * 4 + 0] = v.x;
            av[q * 4 + 1] = v.y;
            av[q * 4 + 2] = v.z;
            av[q * 4 + 3] = v.w;
        }
        union {
            __bf16 b[16];
            uint4 u[2];
        } cv;
#pragma unroll
        for (int e = 0; e < 16; ++e) cv.b[e] = (__bf16)av[e];
        *reinterpret_cast<uint4*>(&As[sr][sh * 16]) = cv.u[0];
        *reinterpret_cast<uint4*>(&As[sr][sh * 16 + 8]) = cv.u[1];
        if (tid < 128) {
            const uint4 bv0 = *reinterpret_cast<const uint4*>(bp + k0);
            const uint4 bv1 = *reinterpret_cast<const uint4*>(bp + k0 + 8);
            *reinterpret_cast<uint4*>(&Bs[sr & 63][sh * 16]) = bv0;
            *reinterpret_cast<uint4*>(&Bs[sr & 63][sh * 16 + 8]) = bv1;
        }
        __syncthreads();
        bf16x8 af[2], bfv[4];
#pragma unroll
        for (int mt = 0; mt < 2; ++mt)
            af[mt] =
                *reinterpret_cast<const bf16x8*>(&As[w * 32 + mt * 16 + fr][kg]);
#pragma unroll
        for (int nt = 0; nt < 4; ++nt)
            bfv[nt] = *reinterpret_cast<const bf16x8*>(&Bs[nt * 16 + fr][kg]);
#pragma unroll
        for (int mt = 0; mt < 2; ++mt)
#pragma unroll
            for (int nt = 0; nt < 4; ++nt)
                acc[mt][nt] = __builtin_amdgcn_mfma_f32_16x16x32_bf16(
                    af[mt], bfv[nt], acc[mt][nt], 0, 0, 0);
        __syncthreads();
    }
    const int rg = (l >> 4) * 4;
#pragma unroll
    for (int nt = 0; nt < 4; ++nt) {
        const int col = nt * 16 + fr;
        const float bb = bias[col];
        const float gs = gamma[col] * RS;
        const float bt = beta[col];
#pragma unroll
        for (int mt = 0; mt < 2; ++mt) {
#pragma unroll
            for (int r = 0; r < 4; ++r) {
                const long row = row0 + w * 32 + mt * 16 + rg + r;
                float v = acc[mt][nt][r] + bb;
                v = eluf(v) * gs + bt;
                outp[row * Ncols + col] = __float2bfloat16(v);
            }
        }
    }
}

// ---------------------------------------------------------------------------
// xchain (R14 winner): fused Xc -> X1 -> X2, LDS-persistent 128x256 panel.
// 256 blocks x 1024 threads (4x4 waves, 32x64 quadrants).
// ---------------------------------------------------------------------------
__global__ __launch_bounds__(1024) void xchain_kernel(
    const __hip_bfloat16* __restrict__ PLB, const __hip_bfloat16* __restrict__ cWt,
    const float* __restrict__ cb, const __hip_bfloat16* __restrict__ d1Wt,
    const float* __restrict__ d1b, const __hip_bfloat16* __restrict__ d2Wt,
    const float* __restrict__ d2b, __hip_bfloat16* __restrict__ X2B) {
    __shared__ __bf16 Ap[128][264];
    __shared__ __bf16 Bs[256][40];
    const int tid = threadIdx.x;
    const int w = tid >> 6, l = tid & 63;
    const int wm = w >> 2, wn = w & 3;
    const long row0 = (long)blockIdx.x * 128;
    const int fr = l & 15, kg = (l >> 4) * 8, rg = (l >> 4) * 4;

    {
        const int r = tid >> 3, q = tid & 7;
        *reinterpret_cast<uint4*>(&Ap[r][q * 8]) =
            *reinterpret_cast<const uint4*>(PLB + (row0 + r) * 64 + q * 8);
    }
    __syncthreads();

    auto layer = [&](const __hip_bfloat16* __restrict__ Wt,
                     const float* __restrict__ bias, int K, bool act,
                     bool last) {
        f32x4 acc[2][4] = {};
        for (int k0 = 0; k0 < K; k0 += 32) {
            {
                const int col = tid >> 2, q = tid & 3;
                *reinterpret_cast<uint4*>(&Bs[col][q * 8]) =
                    *reinterpret_cast<const uint4*>(Wt + (long)col * K + k0 +
                                                    q * 8);
            }
            __syncthreads();
            bf16x8 af[2], bfv[4];
#pragma unroll
            for (int mt = 0; mt < 2; ++mt)
                af[mt] = *reinterpret_cast<const bf16x8*>(
                    &Ap[wm * 32 + mt * 16 + fr][k0 + kg]);
#pragma unroll
            for (int nt = 0; nt < 4; ++nt)
                bfv[nt] = *reinterpret_cast<const bf16x8*>(
                    &Bs[wn * 64 + nt * 16 + fr][kg]);
#pragma unroll
            for (int mt = 0; mt < 2; ++mt)
#pragma unroll
                for (int nt = 0; nt < 4; ++nt)
                    acc[mt][nt] = __builtin_amdgcn_mfma_f32_16x16x32_bf16(
                        af[mt], bfv[nt], acc[mt][nt], 0, 0, 0);
            __syncthreads();
        }
#pragma unroll
        for (int nt = 0; nt < 4; ++nt) {
            const int col = wn * 64 + nt * 16 + fr;
            const float bb = bias[col];
#pragma unroll
            for (int mt = 0; mt < 2; ++mt) {
#pragma unroll
                for (int r = 0; r < 4; ++r) {
                    const int row = wm * 32 + mt * 16 + rg + r;
                    float v = acc[mt][nt][r] + bb;
                    if (act) v = eluf(v);
                    const __bf16 h = (__bf16)v;
                    if (last)
                        X2B[(row0 + row) * 256 + col] =
                            *reinterpret_cast<const __hip_bfloat16*>(&h);
                    else
                        Ap[row][col] = h;
                }
            }
        }
        __syncthreads();
    };

    layer(cWt, cb, 64, true, false);
    layer(d1Wt, d1b, 256, true, false);
    layer(d2Wt, d2b, 256, false, true);
}

// ---------------------------------------------------------------------------
// Final per-point stage v12: v11 + fcat XOR-swizzle (16B half-swap on row
// bit2 -> free 2-way banks) + FUSED pw GEMM (block's 16 dw rows -> 16x128
// output via MFMA; partner-wave K-split reduce through LDS overlay on dead
// fcat; writes d_out f32 directly). 3 barriers total.
// NOTE: no 2nd launch_bounds arg (R4: clamp -> spill).
// ---------------------------------------------------------------------------
__global__ __launch_bounds__(1024) void final_stage_kernel(
    const __hip_bfloat16* __restrict__ X2B,  // [32768][256] bf16
    const float* __restrict__ pts_local,     // [32768][48] (k*3+d)
    const int* __restrict__ pts_idx,
    const __hip_bfloat16* __restrict__ fts_lB,  // [131072][64] bf16
    const float* __restrict__ d1_W, const float* __restrict__ d1_b,
    const float* __restrict__ d1_g, const float* __restrict__ d1_bt,
    const __hip_bfloat16* __restrict__ d2pWt,  // [32 c][32 q] bf16
    const float* __restrict__ d2_b, const float* __restrict__ d2_g,
    const float* __restrict__ d2_bt, const float* __restrict__ dw_W,
    const float* __restrict__ dw_b,
    const __hip_bfloat16* __restrict__ pwWt,  // [128][192] bf16
    const float* __restrict__ pw_b, const float* __restrict__ sep_g,
    const float* __restrict__ sep_bt,
    float* __restrict__ out)  // [32768][128] f32
{
    __shared__ __bf16 fcatF[16 * 96 * 16];  // 49152 B (swizzled), wave-private
    __shared__ __bf16 dws[16][200];         // 6400 B: block's dw rows (+bias)
    __shared__ float dwT[96][36];           // 13824 B
    __shared__ float wd1[6][32];
    __shared__ float d2e[3][32];
    __shared__ float dwbs[192];

    const int tid = threadIdx.x;
    const int w = tid >> 6, l = tid & 63;

    // ---- block-level weight staging (barrier 1) ----
    for (int i = tid; i < 3072; i += 1024) dwT[i >> 5][i & 31] = dw_W[i];
    if (tid < 96) wd1[tid >> 5][tid & 31] = d1_W[tid];
    else if (tid < 128) wd1[3][tid & 31] = d1_b[tid & 31];
    else if (tid < 160) wd1[4][tid & 31] = d1_g[tid & 31] * RS;
    else if (tid < 192) wd1[5][tid & 31] = d1_bt[tid & 31];
    else if (tid < 224) d2e[0][tid & 31] = d2_b[tid & 31];
    else if (tid < 256) d2e[1][tid & 31] = d2_g[tid & 31] * RS;
    else if (tid < 288) d2e[2][tid & 31] = d2_bt[tid & 31];
    else if (tid < 480) dwbs[tid - 288] = dw_b[tid - 288];
    __syncthreads();

    const int obid = blockIdx.x;
    const int bid = (obid & 7) * 256 + (obid >> 3);  // bijective, 2048%8==0
    const int gp = bid * 16 + w;
    const int ugp = __builtin_amdgcn_readfirstlane(gp);
    const int n = ugp >> 11;
    const int fr = l & 15;
    const int kg = (l >> 4) * 8;
    const int kk = kg & 15;
    const unsigned msk = (l < 32) ? 0xFFFFFFFFu : 0u;
    const int rg4 = (l >> 4) * 4;
    const int colg = (l < 32) ? (32 + l) : (l - 32);
    const __hip_bfloat16* __restrict__ fbase =
        fts_lB + (long)n * 8192 * 64 + colg;

    // fcat elem index with 16B half-swap swizzle on row bit2
#define FIDX(W, ROW, E) ((((W)*96 + (ROW)) << 4) + ((E) ^ (((ROW)&4) << 1)))

    // ---- fts gather: lane owns bf16 col colg, 16 rows (idx via s_load) ----
    const int* __restrict__ ip = pts_idx + (long)ugp * 32;
    unsigned fg[16];
#pragma unroll
    for (int j = 0; j < 16; ++j)
        fg[j] = *reinterpret_cast<const unsigned short*>(
            &fbase[(long)ip[2 * j] * 64]);

    const float* __restrict__ pp = pts_local + (long)ugp * 48 + fr * 3;
    const float plA0 = pp[0], plA1 = pp[1], plA2 = pp[2];

    // ---- l0 row-owner A-frag ----
    bf16x8 a_l0;
#pragma unroll
    for (int jj = 0; jj < 8; ++jj) {
        const int q = kg + jj;
        float a = wd1[3][q];
        a = fmaf(plA0, wd1[0][q], a);
        a = fmaf(plA1, wd1[1][q], a);
        a = fmaf(plA2, wd1[2][q], a);
        a = eluf(a);
        a = a * wd1[4][q] + wd1[5][q];
        a_l0[jj] = (__bf16)a;
    }

    // ---- lifted = l0 @ d2_W via 2 MFMA -> fcat cols 0..31 ----
    {
        const bf16x8 b0 =
            *reinterpret_cast<const bf16x8*>(d2pWt + (0 + fr) * 32 + kg);
        const bf16x8 b1 =
            *reinterpret_cast<const bf16x8*>(d2pWt + (16 + fr) * 32 + kg);
        f32x4 lif0 = {}, lif1 = {};
        lif0 = __builtin_amdgcn_mfma_f32_16x16x32_bf16(a_l0, b0, lif0, 0, 0, 0);
        lif1 = __builtin_amdgcn_mfma_f32_16x16x32_bf16(a_l0, b1, lif1, 0, 0, 0);
#pragma unroll
        for (int f = 0; f < 2; ++f) {
            const int c = f * 16 + fr;
            const float bb = d2e[0][c & 31], gs = d2e[1][c & 31],
                        bt = d2e[2][c & 31];
            const f32x4 dd = f ? lif1 : lif0;
            unsigned short pk[4];
#pragma unroll
            for (int r = 0; r < 4; ++r) {
                float v = dd[r] + bb;
                v = eluf(v) * gs + bt;
                const __bf16 h = (__bf16)v;
                pk[r] = *reinterpret_cast<const unsigned short*>(&h);
            }
            *reinterpret_cast<uint2*>(&fcatF[FIDX(w, c, rg4)]) =
                make_uint2((unsigned)pk[0] | ((unsigned)pk[1] << 16),
                           (unsigned)pk[2] | ((unsigned)pk[3] << 16));
        }
    }

    // ---- fg (bf16 bits) -> fcat[32+colg][0..15] (2 x ds_write_b128) ----
    {
        const uint4 lo = make_uint4(fg[0] | (fg[1] << 16), fg[2] | (fg[3] << 16),
                                    fg[4] | (fg[5] << 16), fg[6] | (fg[7] << 16));
        const uint4 hi =
            make_uint4(fg[8] | (fg[9] << 16), fg[10] | (fg[11] << 16),
                       fg[12] | (fg[13] << 16), fg[14] | (fg[15] << 16));
        const int row = 32 + colg;
        *reinterpret_cast<uint4*>(&fcatF[FIDX(w, row, 0)]) = lo;
        *reinterpret_cast<uint4*>(&fcatF[FIDX(w, row, 8)]) = hi;
    }

    // ---- A-frag: X row fr (zero k>=16 half via mask) ----
    u32x4 axu =
        *reinterpret_cast<const u32x4*>(X2B + (long)ugp * 256 + fr * 16 + kk);
    axu &= msk;
    const bf16x8 ax = *reinterpret_cast<const bf16x8*>(&axu);

    // ---- fts_X: 6 B-frags from fcat + 6 MFMA ----
    f32x4 acc[6];
#pragma unroll
    for (int f = 0; f < 6; ++f) acc[f] = (f32x4){};
#pragma unroll
    for (int f = 0; f < 6; ++f) {
        u32x4 bu =
            *reinterpret_cast<const u32x4*>(&fcatF[FIDX(w, f * 16 + fr, kk)]);
        bu &= msk;
        const bf16x8 bf = *reinterpret_cast<const bf16x8*>(&bu);
        acc[f] = __builtin_amdgcn_mfma_f32_16x16x32_bf16(ax, bf, acc[f], 0, 0, 0);
    }

    // ---- dw: partials rows rg4..rg4+3, butterfly ----
    float dwv[6][2];
#pragma unroll
    for (int f = 0; f < 6; ++f) {
        const int c = f * 16 + fr;
        const float4 w0 = *reinterpret_cast<const float4*>(&dwT[c][rg4]);
        const float4 w1 = *reinterpret_cast<const float4*>(&dwT[c][16 + rg4]);
        float p0 = acc[f][0] * w0.x;
        p0 = fmaf(acc[f][1], w0.y, p0);
        p0 = fmaf(acc[f][2], w0.z, p0);
        p0 = fmaf(acc[f][3], w0.w, p0);
        float p1 = acc[f][0] * w1.x;
        p1 = fmaf(acc[f][1], w1.y, p1);
        p1 = fmaf(acc[f][2], w1.z, p1);
        p1 = fmaf(acc[f][3], w1.w, p1);
        p0 += __shfl_xor(p0, 16);
        p0 += __shfl_xor(p0, 32);
        p1 += __shfl_xor(p1, 16);
        p1 += __shfl_xor(p1, 32);
        dwv[f][0] = p0;
        dwv[f][1] = p1;
    }
    // stage dw row (bf16 + bias, same rounding as before) into dws[w]
    if (l < 16) {
#pragma unroll
        for (int f = 0; f < 6; ++f) {
            const int c = f * 16 + l;
            __hip_bfloat162 pk;
            pk.x = __float2bfloat16(dwv[f][0] + dwbs[2 * c + 0]);
            pk.y = __float2bfloat16(dwv[f][1] + dwbs[2 * c + 1]);
            *reinterpret_cast<__hip_bfloat162*>(&dws[w][2 * c]) = pk;
        }
    }
    __syncthreads();  // barrier 2: dws complete; fcat reads all done

    // ---- fused pw: out[16][128] = bn(elu(dws(16x192) @ pwWt^T + pw_b)) ----
    // wave w: col-block c8 = w&7, K-half h2 = w>>3 (3 chunks of 32).
    const int c8 = w & 7, h2 = w >> 3;
    f32x4 pacc = {};
#pragma unroll
    for (int t = 0; t < 3; ++t) {
        const int kc = h2 * 3 + t;
        const bf16x8 a =
            *reinterpret_cast<const bf16x8*>(&dws[fr][kc * 32 + kg]);
        const bf16x8 b = *reinterpret_cast<const bf16x8*>(
            pwWt + (long)(c8 * 16 + fr) * 192 + kc * 32 + kg);
        pacc = __builtin_amdgcn_mfma_f32_16x16x32_bf16(a, b, pacc, 0, 0, 0);
    }
    float* red = reinterpret_cast<float*>(fcatF);  // overlay on dead fcat
    if (w >= 8)
        *reinterpret_cast<f32x4*>(&red[(c8 * 64 + l) * 4]) = pacc;
    __syncthreads();  // barrier 3
    if (w < 8) {
        const f32x4 other =
            *reinterpret_cast<const f32x4*>(&red[(c8 * 64 + l) * 4]);
        const int col = c8 * 16 + fr;
        const float bb = pw_b[col];
        const float gs = sep_g[col] * RS;
        const float bt = sep_bt[col];
#pragma unroll
        for (int r = 0; r < 4; ++r) {
            float v = pacc[r] + other[r] + bb;
            v = eluf(v) * gs + bt;
            out[(long)(bid * 16 + rg4 + r) * 128 + col] = v;
        }
    }
#undef FIDX
}

extern "C" void kernel_launch(void* const* d_in, const int* in_sizes, int n_in,
                              void* d_out, int out_size, void* d_ws,
                              size_t ws_size, hipStream_t stream) {
    const float* rep_pts = (const float*)d_in[0];
    const float* pts = (const float*)d_in[1];
    const float* fts = (const float*)d_in[2];
    const int* pts_idx = (const int*)d_in[3];
    const float* dense_W = (const float*)d_in[4];
    const float* dense_b = (const float*)d_in[5];
    const float* dense_g = (const float*)d_in[6];
    const float* dense_bt = (const float*)d_in[7];
    const float* d1_W = (const float*)d_in[8];
    const float* d1_b = (const float*)d_in[9];
    const float* d1_g = (const float*)d_in[10];
    const float* d1_bt = (const float*)d_in[11];
    const float* d2_W = (const float*)d_in[12];
    const float* d2_b = (const float*)d_in[13];
    const float* d2_g = (const float*)d_in[14];
    const float* d2_bt = (const float*)d_in[15];
    const float* xt_cW = (const float*)d_in[16];
    const float* xt_cb = (const float*)d_in[17];
    const float* xt_d1W = (const float*)d_in[18];
    const float* xt_d1b = (const float*)d_in[19];
    const float* xt_d2W = (const float*)d_in[20];
    const float* xt_d2b = (const float*)d_in[21];
    const float* dw_W = (const float*)d_in[22];
    const float* dw_b = (const float*)d_in[23];
    const float* pw_W = (const float*)d_in[24];
    const float* pw_b = (const float*)d_in[25];
    const float* sep_g = (const float*)d_in[26];
    const float* sep_bt = (const float*)d_in[27];

    float* ws = (float*)d_ws;
    __hip_bfloat16* fts_lB = (__hip_bfloat16*)ws;
    __hip_bfloat16* X2Bb = (__hip_bfloat16*)(ws + 8388608);
    __hip_bfloat16* PLB = (__hip_bfloat16*)(ws + 20971520);
    float* pl = ws + 25165824;
    __hip_bfloat16* d1Wt = (__hip_bfloat16*)(ws + 26738688);     // 65536
    __hip_bfloat16* d2Wt = (__hip_bfloat16*)(ws + 26771456);     // 65536
    __hip_bfloat16* pwWt = (__hip_bfloat16*)(ws + 26804224);     // 24576
    __hip_bfloat16* d2pWt = (__hip_bfloat16*)(ws + 26816512);    // 1024
    __hip_bfloat16* denseWt = (__hip_bfloat16*)(ws + 26817024);  // 4096
    __hip_bfloat16* cWt = (__hip_bfloat16*)(ws + 26819072);      // 16384

    // 1) gather (+ fused weight convert): pts_local + PLB
    gather_kernel<<<2048, 256, 0, stream>>>(
        rep_pts, pts, pts_idx, xt_d1W, xt_d2W, pw_W, d2_W, dense_W, xt_cW, pl,
        PLB, d1Wt, d2Wt, pwWt, d2pWt, denseWt, cWt);

    // 2) fts_l = bn(elu(fts @ dense_W + b))  f32-A MFMA TN=64, K=64
    mfma_gemm_f32a64<<<dim3(1024, 1), 256, 0, stream>>>(
        fts, denseWt, dense_b, dense_g, dense_bt, fts_lB, 64, 64);

    // 3) xchain: Xc -> X1 -> X2 fused (panel-persistent LDS)
    xchain_kernel<<<256, 1024, 0, stream>>>(PLB, cWt, xt_cb, d1Wt, xt_d1b,
                                            d2Wt, xt_d2b, X2Bb);

    // 4) final: lifted/gather/fts_X/dw + fused pw -> d_out (f32)
    final_stage_kernel<<<2048, 1024, 0, stream>>>(
        X2Bb, pl, pts_idx, fts_lB, d1_W, d1_b, d1_g, d1_bt, d2pWt, d2_b, d2_g,
        d2_bt, dw_W, dw_b, pwWt, pw_b, sep_g, sep_bt, (float*)d_out);
}

// Round 17
// 87.237 us; speedup vs baseline: 2.2926x; 1.0327x over previous
//
#include <hip/hip_runtime.h>
#include <hip/hip_bf16.h>

#define RS 0.9999950000374998f  // 1/sqrt(1+1e-5)

__device__ __forceinline__ float eluf(float x) {
    return x > 0.0f ? x : __expf(x) - 1.0f;
}

typedef __attribute__((ext_vector_type(8))) __bf16 bf16x8;
typedef __attribute__((ext_vector_type(4))) float f32x4;
typedef __attribute__((ext_vector_type(4))) unsigned int u32x4;

// ---------------------------------------------------------------------------
// prep: ONE kernel, block-range split.
//   blocks [0,2048): per-point gather (pts_local f32 + PLB bf16) and, on
//                    blocks <256, weight convert (d1/d2/pw/d2p/cW -> bf16^T).
//   blocks [2048,3072): fts_l = bn(elu(fts @ dense_W + b)) MFMA (tile 128x64,
//                    K=64), converting dense_W f32->bf16 inline in staging
//                    (no dependency on the convert blocks).
// 256 threads/block.
// ---------------------------------------------------------------------------
__global__ __launch_bounds__(256) void prep_kernel(
    const float* __restrict__ rep_pts, const float* __restrict__ pts,
    const int* __restrict__ pts_idx, const float* __restrict__ fts,
    const float* __restrict__ d1W, const float* __restrict__ d2W,
    const float* __restrict__ pwW, const float* __restrict__ d2Ws,
    const float* __restrict__ cW, const float* __restrict__ denseW,
    const float* __restrict__ dense_b, const float* __restrict__ dense_g,
    const float* __restrict__ dense_bt, float* __restrict__ pts_local,
    __hip_bfloat16* __restrict__ PLB, __hip_bfloat16* __restrict__ d1Wt,
    __hip_bfloat16* __restrict__ d2Wt, __hip_bfloat16* __restrict__ pwWt,
    __hip_bfloat16* __restrict__ d2pWt, __hip_bfloat16* __restrict__ cWt,
    __hip_bfloat16* __restrict__ fts_lB) {
    const int tid = threadIdx.x;
    if (blockIdx.x < 2048) {
        // ---------------- gather (+ convert on first 256 blocks) ----------
        if (blockIdx.x < 256) {
            const int t = blockIdx.x * 256 + tid;
            {
                const int k = t >> 8, n = t & 255;
                d1Wt[n * 256 + k] = __float2bfloat16(d1W[t]);
                d2Wt[n * 256 + k] = __float2bfloat16(d2W[t]);
            }
            if (t < 24576) {
                const int k = t >> 7, n = t & 127;
                pwWt[n * 192 + k] = __float2bfloat16(pwW[t]);
            }
            if (t < 1024) {
                const int q = t >> 5, c = t & 31;
                d2pWt[c * 32 + q] = __float2bfloat16(d2Ws[t]);
            }
            if (t < 16384) {
                const int o = t >> 6, kq = t & 63;
                cWt[t] = (kq < 48) ? __float2bfloat16(cW[o * 48 + kq])
                                   : __float2bfloat16(0.0f);
            }
        }
        const long gp0 = (long)blockIdx.x * 16;
        const int pt = tid >> 4, k = tid & 15;
        const long gp = gp0 + pt;
        const int n = (int)(gp >> 11);
        const int idx = pts_idx[gp * 32 + 2 * k];
        const float* ps = pts + ((long)n * 8192 + idx) * 3;
        const float* rs = rep_pts + gp * 3;
#pragma unroll
        for (int d = 0; d < 3; ++d) {
            const float v = ps[d] - rs[d];
            pts_local[gp * 48 + k * 3 + d] = v;
            PLB[gp * 64 + d * 16 + k] = __float2bfloat16(v);
        }
        PLB[gp * 64 + 48 + k] = __float2bfloat16(0.0f);
        return;
    }
    // ---------------- fts_l MFMA tile (128 rows x 64 cols, K=64) ----------
    __shared__ __bf16 As[128][40];
    __shared__ __bf16 Bs[64][40];
    const int w = tid >> 6, l = tid & 63;
    const long row0 = (long)(blockIdx.x - 2048) * 128;
    const int sr = tid >> 1, sh = tid & 1;
    const int fr = l & 15, kg = (l >> 4) * 8;
    f32x4 acc[2][4] = {};
    const float* __restrict__ ap = fts + (row0 + sr) * 64 + sh * 16;
    for (int k0 = 0; k0 < 64; k0 += 32) {
        float av[16];
#pragma unroll
        for (int q = 0; q < 4; ++q) {
            const float4 v = *reinterpret_cast<const float4*>(ap + k0 + q * 4);
            av[q * 4 + 0] = v.x;
            av[q * 4 + 1] = v.y;
            av[q * 4 + 2] = v.z;
            av[q * 4 + 3] = v.w;
        }
        union {
            __bf16 b[16];
            uint4 u[2];
        } cv;
#pragma unroll
        for (int e = 0; e < 16; ++e) cv.b[e] = (__bf16)av[e];
        *reinterpret_cast<uint4*>(&As[sr][sh * 16]) = cv.u[0];
        *reinterpret_cast<uint4*>(&As[sr][sh * 16 + 8]) = cv.u[1];
        // stage Bs[col][k] = bf16(denseW[(k0+k)*64 + col]) — inline convert
#pragma unroll
        for (int s = 0; s < 8; ++s) {
            const int e = s * 256 + tid;  // 0..2047
            const int kx = e >> 6, col = e & 63;
            Bs[col][kx] = (__bf16)denseW[(k0 + kx) * 64 + col];
        }
        __syncthreads();
        bf16x8 af[2], bfv[4];
#pragma unroll
        for (int mt = 0; mt < 2; ++mt)
            af[mt] =
                *reinterpret_cast<const bf16x8*>(&As[w * 32 + mt * 16 + fr][kg]);
#pragma unroll
        for (int nt = 0; nt < 4; ++nt)
            bfv[nt] = *reinterpret_cast<const bf16x8*>(&Bs[nt * 16 + fr][kg]);
#pragma unroll
        for (int mt = 0; mt < 2; ++mt)
#pragma unroll
            for (int nt = 0; nt < 4; ++nt)
                acc[mt][nt] = __builtin_amdgcn_mfma_f32_16x16x32_bf16(
                    af[mt], bfv[nt], acc[mt][nt], 0, 0, 0);
        __syncthreads();
    }
    const int rg = (l >> 4) * 4;
#pragma unroll
    for (int nt = 0; nt < 4; ++nt) {
        const int col = nt * 16 + fr;
        const float bb = dense_b[col];
        const float gs = dense_g[col] * RS;
        const float bt = dense_bt[col];
#pragma unroll
        for (int mt = 0; mt < 2; ++mt) {
#pragma unroll
            for (int r = 0; r < 4; ++r) {
                const long row = row0 + w * 32 + mt * 16 + rg + r;
                float v = acc[mt][nt][r] + bb;
                v = eluf(v) * gs + bt;
                fts_lB[row * 64 + col] = __float2bfloat16(v);
            }
        }
    }
}

// ---------------------------------------------------------------------------
// xchain v2: fused Xc -> X1 -> X2, LDS-persistent 64x256 activation panel.
// 512 blocks x 512 threads = 8 waves (2x4; each 32x64). LDS 54.3 KB ->
// 2 blocks/CU so barrier stalls of one block hide under the other.
// Same math/roundings as v1.
// ---------------------------------------------------------------------------
__global__ __launch_bounds__(512) void xchain_kernel(
    const __hip_bfloat16* __restrict__ PLB, const __hip_bfloat16* __restrict__ cWt,
    const float* __restrict__ cb, const __hip_bfloat16* __restrict__ d1Wt,
    const float* __restrict__ d1b, const __hip_bfloat16* __restrict__ d2Wt,
    const float* __restrict__ d2b, __hip_bfloat16* __restrict__ X2B) {
    __shared__ __bf16 Ap[64][264];
    __shared__ __bf16 Bs[256][40];
    const int tid = threadIdx.x;
    const int w = tid >> 6, l = tid & 63;
    const int wm = w >> 2, wn = w & 3;
    const long row0 = (long)blockIdx.x * 64;
    const int fr = l & 15, kg = (l >> 4) * 8, rg = (l >> 4) * 4;

    {
        const int r = tid >> 3, q = tid & 7;
        *reinterpret_cast<uint4*>(&Ap[r][q * 8]) =
            *reinterpret_cast<const uint4*>(PLB + (row0 + r) * 64 + q * 8);
    }
    __syncthreads();

    auto layer = [&](const __hip_bfloat16* __restrict__ Wt,
                     const float* __restrict__ bias, int K, bool act,
                     bool last) {
        f32x4 acc[2][4] = {};
        for (int k0 = 0; k0 < K; k0 += 32) {
#pragma unroll
            for (int s = 0; s < 2; ++s) {
                const int i = s * 512 + tid;
                const int col = i >> 2, q = i & 3;
                *reinterpret_cast<uint4*>(&Bs[col][q * 8]) =
                    *reinterpret_cast<const uint4*>(Wt + (long)col * K + k0 +
                                                    q * 8);
            }
            __syncthreads();
            bf16x8 af[2], bfv[4];
#pragma unroll
            for (int mt = 0; mt < 2; ++mt)
                af[mt] = *reinterpret_cast<const bf16x8*>(
                    &Ap[wm * 32 + mt * 16 + fr][k0 + kg]);
#pragma unroll
            for (int nt = 0; nt < 4; ++nt)
                bfv[nt] = *reinterpret_cast<const bf16x8*>(
                    &Bs[wn * 64 + nt * 16 + fr][kg]);
#pragma unroll
            for (int mt = 0; mt < 2; ++mt)
#pragma unroll
                for (int nt = 0; nt < 4; ++nt)
                    acc[mt][nt] = __builtin_amdgcn_mfma_f32_16x16x32_bf16(
                        af[mt], bfv[nt], acc[mt][nt], 0, 0, 0);
            __syncthreads();
        }
#pragma unroll
        for (int nt = 0; nt < 4; ++nt) {
            const int col = wn * 64 + nt * 16 + fr;
            const float bb = bias[col];
#pragma unroll
            for (int mt = 0; mt < 2; ++mt) {
#pragma unroll
                for (int r = 0; r < 4; ++r) {
                    const int row = wm * 32 + mt * 16 + rg + r;
                    float v = acc[mt][nt][r] + bb;
                    if (act) v = eluf(v);
                    const __bf16 h = (__bf16)v;
                    if (last)
                        X2B[(row0 + row) * 256 + col] =
                            *reinterpret_cast<const __hip_bfloat16*>(&h);
                    else
                        Ap[row][col] = h;
                }
            }
        }
        __syncthreads();
    };

    layer(cWt, cb, 64, true, false);
    layer(d1Wt, d1b, 256, true, false);
    layer(d2Wt, d2b, 256, false, true);
}

// ---------------------------------------------------------------------------
// Final per-point stage v12 (R16, unchanged): weight staging in LDS, fcat
// XOR-swizzle, fused pw GEMM writing d_out f32. 3 barriers.
// NOTE: no 2nd launch_bounds arg (R4: clamp -> spill).
// ---------------------------------------------------------------------------
__global__ __launch_bounds__(1024) void final_stage_kernel(
    const __hip_bfloat16* __restrict__ X2B,  // [32768][256] bf16
    const float* __restrict__ pts_local,     // [32768][48] (k*3+d)
    const int* __restrict__ pts_idx,
    const __hip_bfloat16* __restrict__ fts_lB,  // [131072][64] bf16
    const float* __restrict__ d1_W, const float* __restrict__ d1_b,
    const float* __restrict__ d1_g, const float* __restrict__ d1_bt,
    const __hip_bfloat16* __restrict__ d2pWt,  // [32 c][32 q] bf16
    const float* __restrict__ d2_b, const float* __restrict__ d2_g,
    const float* __restrict__ d2_bt, const float* __restrict__ dw_W,
    const float* __restrict__ dw_b,
    const __hip_bfloat16* __restrict__ pwWt,  // [128][192] bf16
    const float* __restrict__ pw_b, const float* __restrict__ sep_g,
    const float* __restrict__ sep_bt,
    float* __restrict__ out)  // [32768][128] f32
{
    __shared__ __bf16 fcatF[16 * 96 * 16];
    __shared__ __bf16 dws[16][200];
    __shared__ float dwT[96][36];
    __shared__ float wd1[6][32];
    __shared__ float d2e[3][32];
    __shared__ float dwbs[192];

    const int tid = threadIdx.x;
    const int w = tid >> 6, l = tid & 63;

    for (int i = tid; i < 3072; i += 1024) dwT[i >> 5][i & 31] = dw_W[i];
    if (tid < 96) wd1[tid >> 5][tid & 31] = d1_W[tid];
    else if (tid < 128) wd1[3][tid & 31] = d1_b[tid & 31];
    else if (tid < 160) wd1[4][tid & 31] = d1_g[tid & 31] * RS;
    else if (tid < 192) wd1[5][tid & 31] = d1_bt[tid & 31];
    else if (tid < 224) d2e[0][tid & 31] = d2_b[tid & 31];
    else if (tid < 256) d2e[1][tid & 31] = d2_g[tid & 31] * RS;
    else if (tid < 288) d2e[2][tid & 31] = d2_bt[tid & 31];
    else if (tid < 480) dwbs[tid - 288] = dw_b[tid - 288];
    __syncthreads();

    const int obid = blockIdx.x;
    const int bid = (obid & 7) * 256 + (obid >> 3);
    const int gp = bid * 16 + w;
    const int ugp = __builtin_amdgcn_readfirstlane(gp);
    const int n = ugp >> 11;
    const int fr = l & 15;
    const int kg = (l >> 4) * 8;
    const int kk = kg & 15;
    const unsigned msk = (l < 32) ? 0xFFFFFFFFu : 0u;
    const int rg4 = (l >> 4) * 4;
    const int colg = (l < 32) ? (32 + l) : (l - 32);
    const __hip_bfloat16* __restrict__ fbase =
        fts_lB + (long)n * 8192 * 64 + colg;

#define FIDX(W, ROW, E) ((((W)*96 + (ROW)) << 4) + ((E) ^ (((ROW)&4) << 1)))

    const int* __restrict__ ip = pts_idx + (long)ugp * 32;
    unsigned fg[16];
#pragma unroll
    for (int j = 0; j < 16; ++j)
        fg[j] = *reinterpret_cast<const unsigned short*>(
            &fbase[(long)ip[2 * j] * 64]);

    const float* __restrict__ pp = pts_local + (long)ugp * 48 + fr * 3;
    const float plA0 = pp[0], plA1 = pp[1], plA2 = pp[2];

    bf16x8 a_l0;
#pragma unroll
    for (int jj = 0; jj < 8; ++jj) {
        const int q = kg + jj;
        float a = wd1[3][q];
        a = fmaf(plA0, wd1[0][q], a);
        a = fmaf(plA1, wd1[1][q], a);
        a = fmaf(plA2, wd1[2][q], a);
        a = eluf(a);
        a = a * wd1[4][q] + wd1[5][q];
        a_l0[jj] = (__bf16)a;
    }

    {
        const bf16x8 b0 =
            *reinterpret_cast<const bf16x8*>(d2pWt + (0 + fr) * 32 + kg);
        const bf16x8 b1 =
            *reinterpret_cast<const bf16x8*>(d2pWt + (16 + fr) * 32 + kg);
        f32x4 lif0 = {}, lif1 = {};
        lif0 = __builtin_amdgcn_mfma_f32_16x16x32_bf16(a_l0, b0, lif0, 0, 0, 0);
        lif1 = __builtin_amdgcn_mfma_f32_16x16x32_bf16(a_l0, b1, lif1, 0, 0, 0);
#pragma unroll
        for (int f = 0; f < 2; ++f) {
            const int c = f * 16 + fr;
            const float bb = d2e[0][c & 31], gs = d2e[1][c & 31],
                        bt = d2e[2][c & 31];
            const f32x4 dd = f ? lif1 : lif0;
            unsigned short pk[4];
#pragma unroll
            for (int r = 0; r < 4; ++r) {
                float v = dd[r] + bb;
                v = eluf(v) * gs + bt;
                const __bf16 h = (__bf16)v;
                pk[r] = *reinterpret_cast<const unsigned short*>(&h);
            }
            *reinterpret_cast<uint2*>(&fcatF[FIDX(w, c, rg4)]) =
                make_uint2((unsigned)pk[0] | ((unsigned)pk[1] << 16),
                           (unsigned)pk[2] | ((unsigned)pk[3] << 16));
        }
    }

    {
        const uint4 lo = make_uint4(fg[0] | (fg[1] << 16), fg[2] | (fg[3] << 16),
                                    fg[4] | (fg[5] << 16), fg[6] | (fg[7] << 16));
        const uint4 hi =
            make_uint4(fg[8] | (fg[9] << 16), fg[10] | (fg[11] << 16),
                       fg[12] | (fg[13] << 16), fg[14] | (fg[15] << 16));
        const int row = 32 + colg;
        *reinterpret_cast<uint4*>(&fcatF[FIDX(w, row, 0)]) = lo;
        *reinterpret_cast<uint4*>(&fcatF[FIDX(w, row, 8)]) = hi;
    }

    u32x4 axu =
        *reinterpret_cast<const u32x4*>(X2B + (long)ugp * 256 + fr * 16 + kk);
    axu &= msk;
    const bf16x8 ax = *reinterpret_cast<const bf16x8*>(&axu);

    f32x4 acc[6];
#pragma unroll
    for (int f = 0; f < 6; ++f) acc[f] = (f32x4){};
#pragma unroll
    for (int f = 0; f < 6; ++f) {
        u32x4 bu =
            *reinterpret_cast<const u32x4*>(&fcatF[FIDX(w, f * 16 + fr, kk)]);
        bu &= msk;
        const bf16x8 bf = *reinterpret_cast<const bf16x8*>(&bu);
        acc[f] = __builtin_amdgcn_mfma_f32_16x16x32_bf16(ax, bf, acc[f], 0, 0, 0);
    }

    float dwv[6][2];
#pragma unroll
    for (int f = 0; f < 6; ++f) {
        const int c = f * 16 + fr;
        const float4 w0 = *reinterpret_cast<const float4*>(&dwT[c][rg4]);
        const float4 w1 = *reinterpret_cast<const float4*>(&dwT[c][16 + rg4]);
        float p0 = acc[f][0] * w0.x;
        p0 = fmaf(acc[f][1], w0.y, p0);
        p0 = fmaf(acc[f][2], w0.z, p0);
        p0 = fmaf(acc[f][3], w0.w, p0);
        float p1 = acc[f][0] * w1.x;
        p1 = fmaf(acc[f][1], w1.y, p1);
        p1 = fmaf(acc[f][2], w1.z, p1);
        p1 = fmaf(acc[f][3], w1.w, p1);
        p0 += __shfl_xor(p0, 16);
        p0 += __shfl_xor(p0, 32);
        p1 += __shfl_xor(p1, 16);
        p1 += __shfl_xor(p1, 32);
        dwv[f][0] = p0;
        dwv[f][1] = p1;
    }
    if (l < 16) {
#pragma unroll
        for (int f = 0; f < 6; ++f) {
            const int c = f * 16 + l;
            __hip_bfloat162 pk;
            pk.x = __float2bfloat16(dwv[f][0] + dwbs[2 * c + 0]);
            pk.y = __float2bfloat16(dwv[f][1] + dwbs[2 * c + 1]);
            *reinterpret_cast<__hip_bfloat162*>(&dws[w][2 * c]) = pk;
        }
    }
    __syncthreads();

    const int c8 = w & 7, h2 = w >> 3;
    f32x4 pacc = {};
#pragma unroll
    for (int t = 0; t < 3; ++t) {
        const int kc = h2 * 3 + t;
        const bf16x8 a =
            *reinterpret_cast<const bf16x8*>(&dws[fr][kc * 32 + kg]);
        const bf16x8 b = *reinterpret_cast<const bf16x8*>(
            pwWt + (long)(c8 * 16 + fr) * 192 + kc * 32 + kg);
        pacc = __builtin_amdgcn_mfma_f32_16x16x32_bf16(a, b, pacc, 0, 0, 0);
    }
    float* red = reinterpret_cast<float*>(fcatF);
    if (w >= 8)
        *reinterpret_cast<f32x4*>(&red[(c8 * 64 + l) * 4]) = pacc;
    __syncthreads();
    if (w < 8) {
        const f32x4 other =
            *reinterpret_cast<const f32x4*>(&red[(c8 * 64 + l) * 4]);
        const int col = c8 * 16 + fr;
        const float bb = pw_b[col];
        const float gs = sep_g[col] * RS;
        const float bt = sep_bt[col];
#pragma unroll
        for (int r = 0; r < 4; ++r) {
            float v = pacc[r] + other[r] + bb;
            v = eluf(v) * gs + bt;
            out[(long)(bid * 16 + rg4 + r) * 128 + col] = v;
        }
    }
#undef FIDX
}

extern "C" void kernel_launch(void* const* d_in, const int* in_sizes, int n_in,
                              void* d_out, int out_size, void* d_ws,
                              size_t ws_size, hipStream_t stream) {
    const float* rep_pts = (const float*)d_in[0];
    const float* pts = (const float*)d_in[1];
    const float* fts = (const float*)d_in[2];
    const int* pts_idx = (const int*)d_in[3];
    const float* dense_W = (const float*)d_in[4];
    const float* dense_b = (const float*)d_in[5];
    const float* dense_g = (const float*)d_in[6];
    const float* dense_bt = (const float*)d_in[7];
    const float* d1_W = (const float*)d_in[8];
    const float* d1_b = (const float*)d_in[9];
    const float* d1_g = (const float*)d_in[10];
    const float* d1_bt = (const float*)d_in[11];
    const float* d2_W = (const float*)d_in[12];
    const float* d2_b = (const float*)d_in[13];
    const float* d2_g = (const float*)d_in[14];
    const float* d2_bt = (const float*)d_in[15];
    const float* xt_cW = (const float*)d_in[16];
    const float* xt_cb = (const float*)d_in[17];
    const float* xt_d1W = (const float*)d_in[18];
    const float* xt_d1b = (const float*)d_in[19];
    const float* xt_d2W = (const float*)d_in[20];
    const float* xt_d2b = (const float*)d_in[21];
    const float* dw_W = (const float*)d_in[22];
    const float* dw_b = (const float*)d_in[23];
    const float* pw_W = (const float*)d_in[24];
    const float* pw_b = (const float*)d_in[25];
    const float* sep_g = (const float*)d_in[26];
    const float* sep_bt = (const float*)d_in[27];

    float* ws = (float*)d_ws;
    __hip_bfloat16* fts_lB = (__hip_bfloat16*)ws;
    __hip_bfloat16* X2Bb = (__hip_bfloat16*)(ws + 8388608);
    __hip_bfloat16* PLB = (__hip_bfloat16*)(ws + 20971520);
    float* pl = ws + 25165824;
    __hip_bfloat16* d1Wt = (__hip_bfloat16*)(ws + 26738688);   // 65536
    __hip_bfloat16* d2Wt = (__hip_bfloat16*)(ws + 26771456);   // 65536
    __hip_bfloat16* pwWt = (__hip_bfloat16*)(ws + 26804224);   // 24576
    __hip_bfloat16* d2pWt = (__hip_bfloat16*)(ws + 26816512);  // 1024
    __hip_bfloat16* cWt = (__hip_bfloat16*)(ws + 26819072);    // 16384

    // 1) prep: gather + weight convert + fts_l (merged, block-range split)
    prep_kernel<<<3072, 256, 0, stream>>>(
        rep_pts, pts, pts_idx, fts, xt_d1W, xt_d2W, pw_W, d2_W, xt_cW, dense_W,
        dense_b, dense_g, dense_bt, pl, PLB, d1Wt, d2Wt, pwWt, d2pWt, cWt,
        fts_lB);

    // 2) xchain: Xc -> X1 -> X2 fused (64-row panels, 2 blocks/CU)
    xchain_kernel<<<512, 512, 0, stream>>>(PLB, cWt, xt_cb, d1Wt, xt_d1b, d2Wt,
                                           xt_d2b, X2Bb);

    // 3) final: lifted/gather/fts_X/dw + fused pw -> d_out (f32)
    final_stage_kernel<<<2048, 1024, 0, stream>>>(
        X2Bb, pl, pts_idx, fts_lB, d1_W, d1_b, d1_g, d1_bt, d2pWt, d2_b, d2_g,
        d2_bt, dw_W, dw_b, pwWt, pw_b, sep_g, sep_bt, (float*)d_out);
}